// Round 1
// baseline (1014.512 us; speedup 1.0000x reference)
//
#include <hip/hip_runtime.h>
#include <math.h>

// Problem dims (fixed)
#define NN 4096     // nodes
#define DD 400      // input feature dim
#define HH 256      // GCN hidden
#define FF 128      // GAT out dim
#define ZZ 64       // latent
#define YY 5        // classes
#define PH 128      // predictor hidden

__device__ __forceinline__ float lrelu(float v) { return v >= 0.f ? v : 0.25f * v; }

// ---------------------------------------------------------------------------
// Batched (z=2 modalities) tiled fp32 GEMM: C = act(A[M,K] @ B[K,N] (+bias))
// BM=BN=64, BK=16, 256 threads, 4x4 micro-tile. All dims divide evenly:
// M=4096, N in {256,128}, K in {400,4096,256} (all multiples of 16/64).
// ---------------------------------------------------------------------------
template<bool FUSE>
__global__ __launch_bounds__(256) void gemm_batch2(
    const float* __restrict__ A0, const float* __restrict__ A1,
    const float* __restrict__ B0, const float* __restrict__ B1,
    const float* __restrict__ bias0, const float* __restrict__ bias1,
    float* __restrict__ C0, float* __restrict__ C1,
    int M, int N, int K)
{
    const float* A   = blockIdx.z ? A1 : A0;
    const float* B   = blockIdx.z ? B1 : B0;
    const float* bias = blockIdx.z ? bias1 : bias0;
    float* C         = blockIdx.z ? C1 : C0;

    __shared__ float As[16][68];  // pad 68: 2-way-max bank aliasing (free), 16B-aligned rows
    __shared__ float Bs[16][68];

    const int tid = threadIdx.x;
    const int tx = tid & 15, ty = tid >> 4;
    const int m0 = blockIdx.y * 64, n0 = blockIdx.x * 64;

    float acc[4][4] = {{0.f}};

    for (int k0 = 0; k0 < K; k0 += 16) {
        #pragma unroll
        for (int i = 0; i < 4; ++i) {
            int idx = tid + i * 256;
            int am = idx >> 4, ak = idx & 15;
            As[ak][am] = A[(size_t)(m0 + am) * K + (k0 + ak)];
        }
        #pragma unroll
        for (int i = 0; i < 4; ++i) {
            int idx = tid + i * 256;
            int bk = idx >> 6, bn = idx & 63;
            Bs[bk][bn] = B[(size_t)(k0 + bk) * N + (n0 + bn)];
        }
        __syncthreads();
        #pragma unroll
        for (int k = 0; k < 16; ++k) {
            float a4[4], b4[4];
            *(float4*)a4 = *(const float4*)&As[k][ty * 4];
            *(float4*)b4 = *(const float4*)&Bs[k][tx * 4];
            #pragma unroll
            for (int i = 0; i < 4; ++i)
                #pragma unroll
                for (int j = 0; j < 4; ++j)
                    acc[i][j] = fmaf(a4[i], b4[j], acc[i][j]);
        }
        __syncthreads();
    }

    #pragma unroll
    for (int i = 0; i < 4; ++i) {
        int row = m0 + ty * 4 + i;
        #pragma unroll
        for (int j = 0; j < 4; ++j) {
            int col = n0 + tx * 4 + j;
            float v = acc[i][j];
            if (FUSE) { v += bias[col]; v = lrelu(v); }
            C[(size_t)row * N + col] = v;
        }
    }
}

// ---------------------------------------------------------------------------
// s1[i] = H[i,:] . a[0:128] ; s2[i] = H[i,:] . a[128:256]   (batched z)
// one wave per row
// ---------------------------------------------------------------------------
__global__ void s12_kernel(
    const float* __restrict__ H0, const float* __restrict__ H1,
    const float* __restrict__ a0, const float* __restrict__ a1,
    float* __restrict__ s1_0, float* __restrict__ s1_1,
    float* __restrict__ s2_0, float* __restrict__ s2_1)
{
    const int z = blockIdx.y;
    const float* H = z ? H1 : H0;
    const float* a = z ? a1 : a0;
    float* s1 = z ? s1_1 : s1_0;
    float* s2 = z ? s2_1 : s2_0;

    const int i = blockIdx.x, t = threadIdx.x;   // 64 threads
    float h0 = H[(size_t)i * FF + t];
    float h1 = H[(size_t)i * FF + 64 + t];
    float v1 = h0 * a[t] + h1 * a[64 + t];
    float v2 = h0 * a[128 + t] + h1 * a[192 + t];
    #pragma unroll
    for (int off = 32; off > 0; off >>= 1) {
        v1 += __shfl_down(v1, off);
        v2 += __shfl_down(v2, off);
    }
    if (t == 0) { s1[i] = v1; s2[i] = v2; }
}

// ---------------------------------------------------------------------------
// Flash-style GAT attention: OUT = lrelu(softmax_row(mask(e)) @ H)
// e_ij = lrelu(s1_i + s2_j), masked to -1e12 where adj_ij <= 0.
// 8 rows per block, 128 threads, 64-column chunks with online softmax.
// ---------------------------------------------------------------------------
__global__ __launch_bounds__(128) void gat_flash(
    const float* __restrict__ adj0, const float* __restrict__ adj1,
    const float* __restrict__ H0,   const float* __restrict__ H1,
    const float* __restrict__ s1_0, const float* __restrict__ s1_1,
    const float* __restrict__ s2_0, const float* __restrict__ s2_1,
    float* __restrict__ O0, float* __restrict__ O1)
{
    const int z = blockIdx.y;
    const float* adj = z ? adj1 : adj0;
    const float* H   = z ? H1 : H0;
    const float* s1v = z ? s1_1 : s1_0;
    const float* s2v = z ? s2_1 : s2_0;
    float* OUT       = z ? O1 : O0;

    __shared__ float Hs[64][128];     // 32 KB chunk of H
    __shared__ float Ws[8][64];       // softmax weights for 8 rows x 64 cols
    __shared__ float scaleRow[8];
    __shared__ float lrow[8];

    const int f = threadIdx.x;          // output column (phase C) / flat id
    const int i0 = blockIdx.x * 8;
    const int r = f >> 4, t = f & 15;   // phase-B mapping: row r, 16 lanes per row

    const float s1r = s1v[i0 + r];
    float acc[8];
    #pragma unroll
    for (int q = 0; q < 8; ++q) acc[q] = 0.f;
    float mreg = -3.0e38f, lreg = 0.f;  // replicated across the 16 lanes of row r

    for (int j0 = 0; j0 < NN; j0 += 64) {
        __syncthreads();  // previous phase C done before overwriting Hs/Ws

        // Phase A: stage H chunk
        #pragma unroll 8
        for (int jj = 0; jj < 64; ++jj)
            Hs[jj][f] = H[(size_t)(j0 + jj) * FF + f];

        // Phase B: e + online softmax bookkeeping (row r, cols t*4..t*4+3)
        float av[4], s2q[4], e[4];
        *(float4*)av  = *(const float4*)&adj[(size_t)(i0 + r) * NN + j0 + t * 4];
        *(float4*)s2q = *(const float4*)&s2v[j0 + t * 4];
        #pragma unroll
        for (int q = 0; q < 4; ++q)
            e[q] = (av[q] > 0.f) ? lrelu(s1r + s2q[q]) : -1e12f;

        float lm = fmaxf(fmaxf(e[0], e[1]), fmaxf(e[2], e[3]));
        lm = fmaxf(lm, __shfl_xor(lm, 1));
        lm = fmaxf(lm, __shfl_xor(lm, 2));
        lm = fmaxf(lm, __shfl_xor(lm, 4));
        lm = fmaxf(lm, __shfl_xor(lm, 8));
        float mnew = fmaxf(mreg, lm);
        float scale = __expf(mreg - mnew);  // 0 if mreg = -3e38
        float wsum = 0.f;
        #pragma unroll
        for (int q = 0; q < 4; ++q) {
            float w = __expf(e[q] - mnew);
            Ws[r][t * 4 + q] = w;
            wsum += w;
        }
        wsum += __shfl_xor(wsum, 1);
        wsum += __shfl_xor(wsum, 2);
        wsum += __shfl_xor(wsum, 4);
        wsum += __shfl_xor(wsum, 8);
        lreg = lreg * scale + wsum;
        mreg = mnew;
        if (t == 0) scaleRow[r] = scale;

        __syncthreads();

        // Phase C: acc[r'] = acc[r']*scale[r'] + sum_j Ws[r'][j]*Hs[j][f]
        #pragma unroll
        for (int q = 0; q < 8; ++q) acc[q] *= scaleRow[q];
        for (int jj4 = 0; jj4 < 64; jj4 += 4) {
            float w[8][4];
            #pragma unroll
            for (int rr = 0; rr < 8; ++rr)
                *(float4*)w[rr] = *(const float4*)&Ws[rr][jj4];
            #pragma unroll
            for (int q = 0; q < 4; ++q) {
                float hv = Hs[jj4 + q][f];
                #pragma unroll
                for (int rr = 0; rr < 8; ++rr)
                    acc[rr] = fmaf(w[rr][q], hv, acc[rr]);
            }
        }
    }

    if (t == 0) lrow[r] = lreg;
    __syncthreads();
    #pragma unroll
    for (int rr = 0; rr < 8; ++rr) {
        float o = acc[rr] / lrow[rr];
        OUT[(size_t)(i0 + rr) * FF + f] = lrelu(o);
    }
}

// ---------------------------------------------------------------------------
// PoE + 3 predictors + softmax, one row per block (128 threads)
// out[i, 0:5]=y(joint), [5:10]=y0, [10:15]=y1
// ---------------------------------------------------------------------------
__global__ __launch_bounds__(128) void final_fused(
    const float* __restrict__ O0, const float* __restrict__ O1,
    const float* __restrict__ mask,
    const float* __restrict__ jpW1, const float* __restrict__ jpb1,
    const float* __restrict__ jpW2, const float* __restrict__ jpb2,
    const float* __restrict__ sW1_0, const float* __restrict__ sb1_0,
    const float* __restrict__ sW2_0, const float* __restrict__ sb2_0,
    const float* __restrict__ sW1_1, const float* __restrict__ sb1_1,
    const float* __restrict__ sW2_1, const float* __restrict__ sb2_1,
    float* __restrict__ out)
{
    __shared__ float zbuf[3][64];    // joint_mu, mu0, mu1
    __shared__ float hbuf[3][128];
    __shared__ float lg[16];

    const int i = blockIdx.x, t = threadIdx.x;

    if (t < 64) {
        float mu0 = O0[(size_t)i * FF + t];
        float lv0 = O0[(size_t)i * FF + 64 + t];
        float mu1 = O1[(size_t)i * FF + t];
        float lv1 = O1[(size_t)i * FF + 64 + t];
        float p0 = 1.f / (__expf(lv0) + 1e-8f);
        float p1 = 1.f / (__expf(lv1) + 1e-8f);
        float mk0 = mask[(size_t)i * 2 + 0];
        float mk1 = mask[(size_t)i * 2 + 1];
        float tmp = 1.f + mk0 * p0 + mk1 * p1;
        float jv = 1.f / (tmp + 1e-8f);
        zbuf[0][t] = jv * (mk0 * p0 * mu0 + mk1 * p1 * mu1);
        zbuf[1][t] = mu0;
        zbuf[2][t] = mu1;
    }
    __syncthreads();

    {
        float s0 = jpb1[t], s1 = sb1_0[t], s2 = sb1_1[t];
        for (int k = 0; k < 64; ++k) {
            float z0 = zbuf[0][k], z1 = zbuf[1][k], z2 = zbuf[2][k];
            s0 = fmaf(z0, jpW1[k * PH + t], s0);
            s1 = fmaf(z1, sW1_0[k * PH + t], s1);
            s2 = fmaf(z2, sW1_1[k * PH + t], s2);
        }
        hbuf[0][t] = lrelu(s0);
        hbuf[1][t] = lrelu(s1);
        hbuf[2][t] = lrelu(s2);
    }
    __syncthreads();

    if (t < 15) {
        int p = t / 5, c = t % 5;
        const float* W2 = (p == 0) ? jpW2 : (p == 1 ? sW2_0 : sW2_1);
        const float* b2 = (p == 0) ? jpb2 : (p == 1 ? sb2_0 : sb2_1);
        float s = b2[c];
        for (int k = 0; k < 128; ++k) s = fmaf(hbuf[p][k], W2[k * YY + c], s);
        lg[t] = s;
    }
    __syncthreads();

    if (t < 3) {
        float mx = -3e38f;
        #pragma unroll
        for (int c = 0; c < 5; ++c) mx = fmaxf(mx, lg[t * 5 + c]);
        float ex[5], sum = 0.f;
        #pragma unroll
        for (int c = 0; c < 5; ++c) { ex[c] = __expf(lg[t * 5 + c] - mx); sum += ex[c]; }
        #pragma unroll
        for (int c = 0; c < 5; ++c)
            out[(size_t)i * 15 + t * 5 + c] = ex[c] / sum;
    }
}

// ---------------------------------------------------------------------------
extern "C" void kernel_launch(void* const* d_in, const int* in_sizes, int n_in,
                              void* d_out, int out_size, void* d_ws, size_t ws_size,
                              hipStream_t stream)
{
    // setup_inputs() dict order: per modality m: x, adj, gc1_W, gc1_b, gc2_W,
    // gc2_b, gat_W, gat_a, spW1, spb1, spW2, spb2; then mask, jpW1..jpb2.
    const float* x[2]   = {(const float*)d_in[0],  (const float*)d_in[12]};
    const float* adj[2] = {(const float*)d_in[1],  (const float*)d_in[13]};
    const float* g1W[2] = {(const float*)d_in[2],  (const float*)d_in[14]};
    const float* g1b[2] = {(const float*)d_in[3],  (const float*)d_in[15]};
    const float* g2W[2] = {(const float*)d_in[4],  (const float*)d_in[16]};
    const float* g2b[2] = {(const float*)d_in[5],  (const float*)d_in[17]};
    const float* gaW[2] = {(const float*)d_in[6],  (const float*)d_in[18]};
    const float* gaA[2] = {(const float*)d_in[7],  (const float*)d_in[19]};
    const float* sW1[2] = {(const float*)d_in[8],  (const float*)d_in[20]};
    const float* sb1[2] = {(const float*)d_in[9],  (const float*)d_in[21]};
    const float* sW2[2] = {(const float*)d_in[10], (const float*)d_in[22]};
    const float* sb2[2] = {(const float*)d_in[11], (const float*)d_in[23]};
    const float* mask   = (const float*)d_in[24];
    const float* jpW1   = (const float*)d_in[25];
    const float* jpb1   = (const float*)d_in[26];
    const float* jpW2   = (const float*)d_in[27];
    const float* jpb2   = (const float*)d_in[28];
    float* out = (float*)d_out;

    float* ws = (float*)d_ws;
    const size_t NH = (size_t)NN * HH;   // 1,048,576
    const size_t NF = (size_t)NN * FF;   // 524,288
    float* S[2]  = {ws + 0 * NH, ws + 1 * NH};
    float* X1[2] = {ws + 2 * NH, ws + 3 * NH};
    float* X2[2] = {ws + 4 * NH, ws + 5 * NH};
    float* Hf[2] = {ws + 6 * NH + 0 * NF, ws + 6 * NH + 1 * NF};
    float* O[2]  = {ws + 6 * NH + 2 * NF, ws + 6 * NH + 3 * NF};
    float* s1p[2] = {ws + 6 * NH + 4 * NF,            ws + 6 * NH + 4 * NF + NN};
    float* s2p[2] = {ws + 6 * NH + 4 * NF + 2 * NN,   ws + 6 * NH + 4 * NF + 3 * NN};
    // total ~ 33.7 MB of fp32 scratch

    // 1. S = x @ gc1_W                       [4096,400]x[400,256]
    gemm_batch2<false><<<dim3(HH / 64, NN / 64, 2), 256, 0, stream>>>(
        x[0], x[1], g1W[0], g1W[1], nullptr, nullptr, S[0], S[1], NN, HH, DD);
    // 2. X1 = lrelu(adj @ S + b1)            [4096,4096]x[4096,256]
    gemm_batch2<true><<<dim3(HH / 64, NN / 64, 2), 256, 0, stream>>>(
        adj[0], adj[1], S[0], S[1], g1b[0], g1b[1], X1[0], X1[1], NN, HH, NN);
    // 3. S = X1 @ gc2_W                      [4096,256]x[256,256]
    gemm_batch2<false><<<dim3(HH / 64, NN / 64, 2), 256, 0, stream>>>(
        X1[0], X1[1], g2W[0], g2W[1], nullptr, nullptr, S[0], S[1], NN, HH, HH);
    // 4. X2 = lrelu(adj @ S + b2)
    gemm_batch2<true><<<dim3(HH / 64, NN / 64, 2), 256, 0, stream>>>(
        adj[0], adj[1], S[0], S[1], g2b[0], g2b[1], X2[0], X2[1], NN, HH, NN);
    // 5. H = X2 @ gat_W                      [4096,256]x[256,128]
    gemm_batch2<false><<<dim3(FF / 64, NN / 64, 2), 256, 0, stream>>>(
        X2[0], X2[1], gaW[0], gaW[1], nullptr, nullptr, Hf[0], Hf[1], NN, FF, HH);
    // 6. s1/s2 = H @ a-halves
    s12_kernel<<<dim3(NN, 2), 64, 0, stream>>>(
        Hf[0], Hf[1], gaA[0], gaA[1], s1p[0], s1p[1], s2p[0], s2p[1]);
    // 7. OUT = lrelu(softmax(mask(e)) @ H)   flash attention
    gat_flash<<<dim3(NN / 8, 2), 128, 0, stream>>>(
        adj[0], adj[1], Hf[0], Hf[1], s1p[0], s1p[1], s2p[0], s2p[1], O[0], O[1]);
    // 8. PoE + predictors + softmax -> out [4096,15]
    final_fused<<<NN, 128, 0, stream>>>(
        O[0], O[1], mask,
        jpW1, jpb1, jpW2, jpb2,
        sW1[0], sb1[0], sW2[0], sb2[0],
        sW1[1], sb1[1], sW2[1], sb2[1],
        out);
}

// Round 3
// 325.979 us; speedup vs baseline: 3.1122x; 3.1122x over previous
//
#include <hip/hip_runtime.h>
#include <math.h>

// Problem dims (fixed)
#define NN 4096     // nodes
#define DD 400      // input feature dim
#define HH 256      // GCN hidden
#define FF 128      // GAT out dim
#define PH 128      // predictor hidden
#define YY 5        // classes

typedef float f32x4v __attribute__((ext_vector_type(4)));
typedef short bf16x8 __attribute__((ext_vector_type(8)));

__device__ __forceinline__ float lrelu(float v) { return v >= 0.f ? v : 0.25f * v; }
// fp32 -> bf16 round-to-nearest-even
__device__ __forceinline__ short f2b(float f) {
    unsigned u = __float_as_uint(f);
    unsigned r = (u + 0x7fffu + ((u >> 16) & 1u)) >> 16;
    return (short)r;
}

// ---------------------------------------------------------------------------
// fp32 tiled GEMM (steps 1,3,5 — small K, cheap).
// ---------------------------------------------------------------------------
template<bool FUSE>
__global__ __launch_bounds__(256) void gemm_batch2(
    const float* __restrict__ A0, const float* __restrict__ A1,
    const float* __restrict__ B0, const float* __restrict__ B1,
    const float* __restrict__ bias0, const float* __restrict__ bias1,
    float* __restrict__ C0, float* __restrict__ C1,
    int M, int N, int K)
{
    const float* A   = blockIdx.z ? A1 : A0;
    const float* B   = blockIdx.z ? B1 : B0;
    const float* bias = blockIdx.z ? bias1 : bias0;
    float* C         = blockIdx.z ? C1 : C0;

    __shared__ float As[16][68];
    __shared__ float Bs[16][68];

    const int tid = threadIdx.x;
    const int tx = tid & 15, ty = tid >> 4;
    const int m0 = blockIdx.y * 64, n0 = blockIdx.x * 64;

    float acc[4][4] = {{0.f}};

    for (int k0 = 0; k0 < K; k0 += 16) {
        #pragma unroll
        for (int i = 0; i < 4; ++i) {
            int idx = tid + i * 256;
            int am = idx >> 4, ak = idx & 15;
            As[ak][am] = A[(size_t)(m0 + am) * K + (k0 + ak)];
        }
        #pragma unroll
        for (int i = 0; i < 4; ++i) {
            int idx = tid + i * 256;
            int bk = idx >> 6, bn = idx & 63;
            Bs[bk][bn] = B[(size_t)(k0 + bk) * N + (n0 + bn)];
        }
        __syncthreads();
        #pragma unroll
        for (int k = 0; k < 16; ++k) {
            float a4[4], b4[4];
            *(float4*)a4 = *(const float4*)&As[k][ty * 4];
            *(float4*)b4 = *(const float4*)&Bs[k][tx * 4];
            #pragma unroll
            for (int i = 0; i < 4; ++i)
                #pragma unroll
                for (int j = 0; j < 4; ++j)
                    acc[i][j] = fmaf(a4[i], b4[j], acc[i][j]);
        }
        __syncthreads();
    }

    #pragma unroll
    for (int i = 0; i < 4; ++i) {
        int row = m0 + ty * 4 + i;
        #pragma unroll
        for (int j = 0; j < 4; ++j) {
            int col = n0 + tx * 4 + j;
            float v = acc[i][j];
            if (FUSE) { v += bias[col]; v = lrelu(v); }
            C[(size_t)row * N + col] = v;
        }
    }
}

// ---------------------------------------------------------------------------
// Transpose + fp32->bf16: in [R,C] f32 -> out [C,R] bf16. grid (C/32, R/32, 2)
// ---------------------------------------------------------------------------
__global__ __launch_bounds__(256) void transpose_f2b(
    const float* __restrict__ in0, const float* __restrict__ in1,
    short* __restrict__ out0, short* __restrict__ out1, int R, int C)
{
    const float* in = blockIdx.z ? in1 : in0;
    short* out      = blockIdx.z ? out1 : out0;
    __shared__ float T[32][33];
    const int r0 = blockIdx.y * 32, c0 = blockIdx.x * 32;
    const int t = threadIdx.x, r = t >> 5, c = t & 31;
    #pragma unroll
    for (int p = 0; p < 4; ++p)
        T[r + p * 8][c] = in[(size_t)(r0 + r + p * 8) * C + c0 + c];
    __syncthreads();
    #pragma unroll
    for (int p = 0; p < 4; ++p)
        out[(size_t)(c0 + r + p * 8) * R + r0 + c] = f2b(T[c][r + p * 8]);
}

// ---------------------------------------------------------------------------
// bf16 MFMA GEMM for X = lrelu(adj @ S + bias)  (steps 2,4)
// A = adj fp32 [4096,4096] (converted to bf16 during reg-staging)
// BT = S^T bf16 [256,4096], C fp32 [4096,256].
// 64x64 tile, BK=64, 256 thr (4 waves, each 32x32), padded LDS (88-elem rows).
// ---------------------------------------------------------------------------
__global__ __launch_bounds__(256) void gemm_mfma_adj(
    const float* __restrict__ A0, const float* __restrict__ A1,
    const short* __restrict__ BT0, const short* __restrict__ BT1,
    const float* __restrict__ bias0, const float* __restrict__ bias1,
    float* __restrict__ C0, float* __restrict__ C1)
{
    const float* A    = blockIdx.z ? A1 : A0;
    const short* BT   = blockIdx.z ? BT1 : BT0;
    const float* bias = blockIdx.z ? bias1 : bias0;
    float* C          = blockIdx.z ? C1 : C0;

    __shared__ short Asl[64 * 88];
    __shared__ short Bsl[64 * 88];

    const int tid = threadIdx.x;
    const int m0 = blockIdx.y * 64, n0 = blockIdx.x * 64;
    const int l = tid & 63, w = tid >> 6;
    const int wr = w >> 1, wc = w & 1;
    const int fr = l & 15, fq = l >> 4;
    const int sr = tid >> 2, sk = (tid & 3) * 16;

    const float* Ap = A  + (size_t)(m0 + sr) * 4096 + sk;
    const short* Bp = BT + (size_t)(n0 + sr) * 4096 + sk;

    f32x4v acc00 = {0.f,0.f,0.f,0.f}, acc01 = {0.f,0.f,0.f,0.f};
    f32x4v acc10 = {0.f,0.f,0.f,0.f}, acc11 = {0.f,0.f,0.f,0.f};

    float4 a0 = *(const float4*)(Ap);
    float4 a1 = *(const float4*)(Ap + 4);
    float4 a2 = *(const float4*)(Ap + 8);
    float4 a3 = *(const float4*)(Ap + 12);
    bf16x8 b0 = *(const bf16x8*)(Bp);
    bf16x8 b1 = *(const bf16x8*)(Bp + 8);

    short* As_w = Asl + sr * 88 + sk;
    short* Bs_w = Bsl + sr * 88 + sk;
    const short* Af = Asl + (wr * 32 + fr) * 88 + fq * 8;
    const short* Bf = Bsl + (wc * 32 + fr) * 88 + fq * 8;

    for (int t = 0; t < 64; ++t) {
        bf16x8 v0, v1;
        v0[0] = f2b(a0.x); v0[1] = f2b(a0.y); v0[2] = f2b(a0.z); v0[3] = f2b(a0.w);
        v0[4] = f2b(a1.x); v0[5] = f2b(a1.y); v0[6] = f2b(a1.z); v0[7] = f2b(a1.w);
        v1[0] = f2b(a2.x); v1[1] = f2b(a2.y); v1[2] = f2b(a2.z); v1[3] = f2b(a2.w);
        v1[4] = f2b(a3.x); v1[5] = f2b(a3.y); v1[6] = f2b(a3.z); v1[7] = f2b(a3.w);
        *(bf16x8*)(As_w)     = v0;
        *(bf16x8*)(As_w + 8) = v1;
        *(bf16x8*)(Bs_w)     = b0;
        *(bf16x8*)(Bs_w + 8) = b1;
        if (t < 63) {                     // next tile's loads; latency hides under MFMA
            const int kk = (t + 1) * 64;
            a0 = *(const float4*)(Ap + kk);
            a1 = *(const float4*)(Ap + kk + 4);
            a2 = *(const float4*)(Ap + kk + 8);
            a3 = *(const float4*)(Ap + kk + 12);
            b0 = *(const bf16x8*)(Bp + kk);
            b1 = *(const bf16x8*)(Bp + kk + 8);
        }
        __syncthreads();
        bf16x8 A00 = *(const bf16x8*)(Af);
        bf16x8 A10 = *(const bf16x8*)(Af + 16 * 88);
        bf16x8 A01 = *(const bf16x8*)(Af + 32);
        bf16x8 A11 = *(const bf16x8*)(Af + 16 * 88 + 32);
        bf16x8 B00 = *(const bf16x8*)(Bf);
        bf16x8 B10 = *(const bf16x8*)(Bf + 16 * 88);
        bf16x8 B01 = *(const bf16x8*)(Bf + 32);
        bf16x8 B11 = *(const bf16x8*)(Bf + 16 * 88 + 32);
        acc00 = __builtin_amdgcn_mfma_f32_16x16x32_bf16(A00, B00, acc00, 0, 0, 0);
        acc01 = __builtin_amdgcn_mfma_f32_16x16x32_bf16(A00, B10, acc01, 0, 0, 0);
        acc10 = __builtin_amdgcn_mfma_f32_16x16x32_bf16(A10, B00, acc10, 0, 0, 0);
        acc11 = __builtin_amdgcn_mfma_f32_16x16x32_bf16(A10, B10, acc11, 0, 0, 0);
        acc00 = __builtin_amdgcn_mfma_f32_16x16x32_bf16(A01, B01, acc00, 0, 0, 0);
        acc01 = __builtin_amdgcn_mfma_f32_16x16x32_bf16(A01, B11, acc01, 0, 0, 0);
        acc10 = __builtin_amdgcn_mfma_f32_16x16x32_bf16(A11, B01, acc10, 0, 0, 0);
        acc11 = __builtin_amdgcn_mfma_f32_16x16x32_bf16(A11, B11, acc11, 0, 0, 0);
        __syncthreads();
    }

    const int colA = n0 + wc * 32 + fr;
    const float bA = bias[colA], bB = bias[colA + 16];
    #pragma unroll
    for (int q = 0; q < 4; ++q) {
        const int r0_ = m0 + wr * 32 + fq * 4 + q;
        const int r1_ = r0_ + 16;
        C[(size_t)r0_ * HH + colA]      = lrelu(acc00[q] + bA);
        C[(size_t)r0_ * HH + colA + 16] = lrelu(acc01[q] + bB);
        C[(size_t)r1_ * HH + colA]      = lrelu(acc10[q] + bA);
        C[(size_t)r1_ * HH + colA + 16] = lrelu(acc11[q] + bB);
    }
}

// ---------------------------------------------------------------------------
// s1[i] = H[i,:] . a[0:128] ; s2[i] = H[i,:] . a[128:256]
// ---------------------------------------------------------------------------
__global__ void s12_kernel(
    const float* __restrict__ H0, const float* __restrict__ H1,
    const float* __restrict__ a0, const float* __restrict__ a1,
    float* __restrict__ s1_0, float* __restrict__ s1_1,
    float* __restrict__ s2_0, float* __restrict__ s2_1)
{
    const int z = blockIdx.y;
    const float* H = z ? H1 : H0;
    const float* a = z ? a1 : a0;
    float* s1 = z ? s1_1 : s1_0;
    float* s2 = z ? s2_1 : s2_0;

    const int i = blockIdx.x, t = threadIdx.x;   // 64 threads
    float h0 = H[(size_t)i * FF + t];
    float h1 = H[(size_t)i * FF + 64 + t];
    float v1 = h0 * a[t] + h1 * a[64 + t];
    float v2 = h0 * a[128 + t] + h1 * a[192 + t];
    #pragma unroll
    for (int off = 32; off > 0; off >>= 1) {
        v1 += __shfl_down(v1, off);
        v2 += __shfl_down(v2, off);
    }
    if (t == 0) { s1[i] = v1; s2[i] = v2; }
}

// ---------------------------------------------------------------------------
// MFMA flash-GAT: O = lrelu(softmax_row(mask(lrelu(s1_i+s2_j))) @ H)
// 32 q-rows/block, 256 thr (4 waves), 64-col chunks, online softmax in regs
// (8 lanes per row), PV via 16x16x32 bf16 MFMA from padded LDS tiles.
// Register double-buffer prefetch of next chunk (adj, s2, H^T).
// ---------------------------------------------------------------------------
struct Pref {
    float4 a0, a1, s0, s1;
    bf16x8 h0, h1, h2, h3;
};

__global__ __launch_bounds__(256) void gat_mfma(
    const float* __restrict__ adj0, const float* __restrict__ adj1,
    const short* __restrict__ HT0, const short* __restrict__ HT1,
    const float* __restrict__ s1_0, const float* __restrict__ s1_1,
    const float* __restrict__ s2_0, const float* __restrict__ s2_1,
    float* __restrict__ O0, float* __restrict__ O1)
{
    const int z = blockIdx.y;
    const float* adjp = z ? adj1 : adj0;
    const short* HTp  = z ? HT1 : HT0;
    const float* s1v  = z ? s1_1 : s1_0;
    const float* s2v  = z ? s2_1 : s2_0;
    float* Op         = z ? O1 : O0;

    __shared__ short Pl[32 * 88];    // P tile (bf16), padded rows
    __shared__ short HTl[128 * 88];  // H^T tile (bf16), padded rows
    __shared__ float scl[32];
    __shared__ float lrw[32];

    const int tid = threadIdx.x;
    const int i0 = blockIdx.x * 32;
    const int r = tid >> 3, cg = tid & 7, c0 = cg * 8;
    const int l = tid & 63, w = tid >> 6;
    const int fr = l & 15, fq = l >> 4;

    const float s1r = s1v[i0 + r];
    float mrun = -3.0e38f, lsum = 0.f;
    f32x4v acc00 = {0.f,0.f,0.f,0.f}, acc01 = {0.f,0.f,0.f,0.f};
    f32x4v acc10 = {0.f,0.f,0.f,0.f}, acc11 = {0.f,0.f,0.f,0.f};

    const float* adjrow = adjp + (size_t)(i0 + r) * 4096 + c0;
    const short* htrow  = HTp + (size_t)r * 4096 + c0;

    Pref PA, PB;

    auto loadr = [&](Pref& P, int J) {
        P.a0 = *(const float4*)(adjrow + J);
        P.a1 = *(const float4*)(adjrow + J + 4);
        P.s0 = *(const float4*)(s2v + J + c0);
        P.s1 = *(const float4*)(s2v + J + c0 + 4);
        P.h0 = *(const bf16x8*)(htrow + J);
        P.h1 = *(const bf16x8*)(htrow + J + 32 * 4096);
        P.h2 = *(const bf16x8*)(htrow + J + 64 * 4096);
        P.h3 = *(const bf16x8*)(htrow + J + 96 * 4096);
    };

    auto process = [&](Pref& P) {
        float e0 = (P.a0.x > 0.f) ? lrelu(s1r + P.s0.x) : -1e12f;
        float e1 = (P.a0.y > 0.f) ? lrelu(s1r + P.s0.y) : -1e12f;
        float e2 = (P.a0.z > 0.f) ? lrelu(s1r + P.s0.z) : -1e12f;
        float e3 = (P.a0.w > 0.f) ? lrelu(s1r + P.s0.w) : -1e12f;
        float e4 = (P.a1.x > 0.f) ? lrelu(s1r + P.s1.x) : -1e12f;
        float e5 = (P.a1.y > 0.f) ? lrelu(s1r + P.s1.y) : -1e12f;
        float e6 = (P.a1.z > 0.f) ? lrelu(s1r + P.s1.z) : -1e12f;
        float e7 = (P.a1.w > 0.f) ? lrelu(s1r + P.s1.w) : -1e12f;
        float lm = fmaxf(fmaxf(fmaxf(e0, e1), fmaxf(e2, e3)),
                         fmaxf(fmaxf(e4, e5), fmaxf(e6, e7)));
        lm = fmaxf(lm, __shfl_xor(lm, 1));
        lm = fmaxf(lm, __shfl_xor(lm, 2));
        lm = fmaxf(lm, __shfl_xor(lm, 4));
        float mnew = fmaxf(mrun, lm);
        float sc = __expf(mrun - mnew);
        float w0 = __expf(e0 - mnew), w1 = __expf(e1 - mnew);
        float w2 = __expf(e2 - mnew), w3 = __expf(e3 - mnew);
        float w4 = __expf(e4 - mnew), w5 = __expf(e5 - mnew);
        float w6 = __expf(e6 - mnew), w7 = __expf(e7 - mnew);
        float wsm = ((w0 + w1) + (w2 + w3)) + ((w4 + w5) + (w6 + w7));
        wsm += __shfl_xor(wsm, 1); wsm += __shfl_xor(wsm, 2); wsm += __shfl_xor(wsm, 4);
        lsum = lsum * sc + wsm; mrun = mnew;
        __syncthreads();   // previous MFMA reads done before overwriting tiles
        bf16x8 wv;
        wv[0] = f2b(w0); wv[1] = f2b(w1); wv[2] = f2b(w2); wv[3] = f2b(w3);
        wv[4] = f2b(w4); wv[5] = f2b(w5); wv[6] = f2b(w6); wv[7] = f2b(w7);
        *(bf16x8*)(Pl + r * 88 + c0) = wv;
        *(bf16x8*)(HTl + (r +  0) * 88 + c0) = P.h0;
        *(bf16x8*)(HTl + (r + 32) * 88 + c0) = P.h1;
        *(bf16x8*)(HTl + (r + 64) * 88 + c0) = P.h2;
        *(bf16x8*)(HTl + (r + 96) * 88 + c0) = P.h3;
        if (cg == 0) scl[r] = sc;
        __syncthreads();
        float q0 = scl[fq * 4 + 0], q1 = scl[fq * 4 + 1];
        float q2 = scl[fq * 4 + 2], q3 = scl[fq * 4 + 3];
        float p0 = scl[16 + fq * 4 + 0], p1 = scl[16 + fq * 4 + 1];
        float p2 = scl[16 + fq * 4 + 2], p3 = scl[16 + fq * 4 + 3];
        acc00[0] *= q0; acc00[1] *= q1; acc00[2] *= q2; acc00[3] *= q3;
        acc01[0] *= q0; acc01[1] *= q1; acc01[2] *= q2; acc01[3] *= q3;
        acc10[0] *= p0; acc10[1] *= p1; acc10[2] *= p2; acc10[3] *= p3;
        acc11[0] *= p0; acc11[1] *= p1; acc11[2] *= p2; acc11[3] *= p3;
        const short* Af = Pl + fr * 88 + fq * 8;
        const short* Bf = HTl + (w * 32 + fr) * 88 + fq * 8;
        bf16x8 A00 = *(const bf16x8*)(Af);
        bf16x8 A10 = *(const bf16x8*)(Af + 16 * 88);
        bf16x8 A01 = *(const bf16x8*)(Af + 32);
        bf16x8 A11 = *(const bf16x8*)(Af + 16 * 88 + 32);
        bf16x8 B00 = *(const bf16x8*)(Bf);
        bf16x8 B10 = *(const bf16x8*)(Bf + 16 * 88);
        bf16x8 B01 = *(const bf16x8*)(Bf + 32);
        bf16x8 B11 = *(const bf16x8*)(Bf + 16 * 88 + 32);
        acc00 = __builtin_amdgcn_mfma_f32_16x16x32_bf16(A00, B00, acc00, 0, 0, 0);
        acc01 = __builtin_amdgcn_mfma_f32_16x16x32_bf16(A00, B10, acc01, 0, 0, 0);
        acc10 = __builtin_amdgcn_mfma_f32_16x16x32_bf16(A10, B00, acc10, 0, 0, 0);
        acc11 = __builtin_amdgcn_mfma_f32_16x16x32_bf16(A10, B10, acc11, 0, 0, 0);
        acc00 = __builtin_amdgcn_mfma_f32_16x16x32_bf16(A01, B01, acc00, 0, 0, 0);
        acc01 = __builtin_amdgcn_mfma_f32_16x16x32_bf16(A01, B11, acc01, 0, 0, 0);
        acc10 = __builtin_amdgcn_mfma_f32_16x16x32_bf16(A11, B01, acc10, 0, 0, 0);
        acc11 = __builtin_amdgcn_mfma_f32_16x16x32_bf16(A11, B11, acc11, 0, 0, 0);
    };

    loadr(PA, 0);
    for (int it = 0; it < 32; ++it) {
        const int j0 = it * 128;
        loadr(PB, j0 + 64);
        process(PA);
        if (it < 31) loadr(PA, j0 + 128);
        process(PB);
    }

    if (cg == 0) lrw[r] = lsum;
    __syncthreads();
    const int col = w * 32 + fr;
    #pragma unroll
    for (int q = 0; q < 4; ++q) {
        const int rl0 = fq * 4 + q, rl1 = 16 + fq * 4 + q;
        Op[(size_t)(i0 + rl0) * FF + col]      = lrelu(acc00[q] / lrw[rl0]);
        Op[(size_t)(i0 + rl0) * FF + col + 16] = lrelu(acc01[q] / lrw[rl0]);
        Op[(size_t)(i0 + rl1) * FF + col]      = lrelu(acc10[q] / lrw[rl1]);
        Op[(size_t)(i0 + rl1) * FF + col + 16] = lrelu(acc11[q] / lrw[rl1]);
    }
}

// ---------------------------------------------------------------------------
// PoE + 3 predictors + softmax (unchanged)
// ---------------------------------------------------------------------------
__global__ __launch_bounds__(128) void final_fused(
    const float* __restrict__ O0, const float* __restrict__ O1,
    const float* __restrict__ mask,
    const float* __restrict__ jpW1, const float* __restrict__ jpb1,
    const float* __restrict__ jpW2, const float* __restrict__ jpb2,
    const float* __restrict__ sW1_0, const float* __restrict__ sb1_0,
    const float* __restrict__ sW2_0, const float* __restrict__ sb2_0,
    const float* __restrict__ sW1_1, const float* __restrict__ sb1_1,
    const float* __restrict__ sW2_1, const float* __restrict__ sb2_1,
    float* __restrict__ out)
{
    __shared__ float zbuf[3][64];
    __shared__ float hbuf[3][128];
    __shared__ float lg[16];

    const int i = blockIdx.x, t = threadIdx.x;

    if (t < 64) {
        float mu0 = O0[(size_t)i * FF + t];
        float lv0 = O0[(size_t)i * FF + 64 + t];
        float mu1 = O1[(size_t)i * FF + t];
        float lv1 = O1[(size_t)i * FF + 64 + t];
        float p0 = 1.f / (__expf(lv0) + 1e-8f);
        float p1 = 1.f / (__expf(lv1) + 1e-8f);
        float mk0 = mask[(size_t)i * 2 + 0];
        float mk1 = mask[(size_t)i * 2 + 1];
        float tmp = 1.f + mk0 * p0 + mk1 * p1;
        float jv = 1.f / (tmp + 1e-8f);
        zbuf[0][t] = jv * (mk0 * p0 * mu0 + mk1 * p1 * mu1);
        zbuf[1][t] = mu0;
        zbuf[2][t] = mu1;
    }
    __syncthreads();

    {
        float s0 = jpb1[t], s1 = sb1_0[t], s2 = sb1_1[t];
        for (int k = 0; k < 64; ++k) {
            float z0 = zbuf[0][k], z1 = zbuf[1][k], z2 = zbuf[2][k];
            s0 = fmaf(z0, jpW1[k * PH + t], s0);
            s1 = fmaf(z1, sW1_0[k * PH + t], s1);
            s2 = fmaf(z2, sW1_1[k * PH + t], s2);
        }
        hbuf[0][t] = lrelu(s0);
        hbuf[1][t] = lrelu(s1);
        hbuf[2][t] = lrelu(s2);
    }
    __syncthreads();

    if (t < 15) {
        int p = t / 5, c = t % 5;
        const float* W2 = (p == 0) ? jpW2 : (p == 1 ? sW2_0 : sW2_1);
        const float* b2 = (p == 0) ? jpb2 : (p == 1 ? sb2_0 : sb2_1);
        float s = b2[c];
        for (int k = 0; k < 128; ++k) s = fmaf(hbuf[p][k], W2[k * YY + c], s);
        lg[t] = s;
    }
    __syncthreads();

    if (t < 3) {
        float mx = -3e38f;
        #pragma unroll
        for (int c = 0; c < 5; ++c) mx = fmaxf(mx, lg[t * 5 + c]);
        float ex[5], sum = 0.f;
        #pragma unroll
        for (int c = 0; c < 5; ++c) { ex[c] = __expf(lg[t * 5 + c] - mx); sum += ex[c]; }
        #pragma unroll
        for (int c = 0; c < 5; ++c)
            out[(size_t)i * 15 + t * 5 + c] = ex[c] / sum;
    }
}

// ---------------------------------------------------------------------------
extern "C" void kernel_launch(void* const* d_in, const int* in_sizes, int n_in,
                              void* d_out, int out_size, void* d_ws, size_t ws_size,
                              hipStream_t stream)
{
    const float* x[2]   = {(const float*)d_in[0],  (const float*)d_in[12]};
    const float* adj[2] = {(const float*)d_in[1],  (const float*)d_in[13]};
    const float* g1W[2] = {(const float*)d_in[2],  (const float*)d_in[14]};
    const float* g1b[2] = {(const float*)d_in[3],  (const float*)d_in[15]};
    const float* g2W[2] = {(const float*)d_in[4],  (const float*)d_in[16]};
    const float* g2b[2] = {(const float*)d_in[5],  (const float*)d_in[17]};
    const float* gaW[2] = {(const float*)d_in[6],  (const float*)d_in[18]};
    const float* gaA[2] = {(const float*)d_in[7],  (const float*)d_in[19]};
    const float* sW1[2] = {(const float*)d_in[8],  (const float*)d_in[20]};
    const float* sb1[2] = {(const float*)d_in[9],  (const float*)d_in[21]};
    const float* sW2[2] = {(const float*)d_in[10], (const float*)d_in[22]};
    const float* sb2[2] = {(const float*)d_in[11], (const float*)d_in[23]};
    const float* mask   = (const float*)d_in[24];
    const float* jpW1   = (const float*)d_in[25];
    const float* jpb1   = (const float*)d_in[26];
    const float* jpW2   = (const float*)d_in[27];
    const float* jpb2   = (const float*)d_in[28];
    float* out = (float*)d_out;

    float* ws = (float*)d_ws;
    const size_t NH = (size_t)NN * HH;   // 1,048,576
    const size_t NF = (size_t)NN * FF;   //   524,288
    float* Sb[2] = {ws,          ws + NH};        // S / S2 / H (fp32)
    float* Xb[2] = {ws + 2 * NH, ws + 3 * NH};    // X1 / X2 / O (fp32)
    short* STb   = (short*)(ws + 4 * NH);
    short* ST[2] = {STb, STb + NH};               // S^T bf16 [256,4096]
    short* HT[2] = {STb + 2 * NH, STb + 2 * NH + NF}; // H^T bf16 [128,4096]
    float* sv    = ws + 5 * NH + NF;
    float* s1p[2] = {sv,            sv + NN};
    float* s2p[2] = {sv + 2 * NN,   sv + 3 * NN};
    // total: 5*NH + NF + 4*NN floats ~ 23.1 MB

    // 1. S = x @ gc1_W            [4096,400]x[400,256]  (fp32 VALU)
    gemm_batch2<false><<<dim3(HH / 64, NN / 64, 2), 256, 0, stream>>>(
        x[0], x[1], g1W[0], g1W[1], nullptr, nullptr, Sb[0], Sb[1], NN, HH, DD);
    // 2a. S^T bf16
    transpose_f2b<<<dim3(HH / 32, NN / 32, 2), 256, 0, stream>>>(
        Sb[0], Sb[1], ST[0], ST[1], NN, HH);
    // 2b. X1 = lrelu(adj @ S + b1)   (bf16 MFMA)
    gemm_mfma_adj<<<dim3(HH / 64, NN / 64, 2), 256, 0, stream>>>(
        adj[0], adj[1], ST[0], ST[1], g1b[0], g1b[1], Xb[0], Xb[1]);
    // 3. S2 = X1 @ gc2_W          [4096,256]x[256,256]  (fp32 VALU)
    gemm_batch2<false><<<dim3(HH / 64, NN / 64, 2), 256, 0, stream>>>(
        Xb[0], Xb[1], g2W[0], g2W[1], nullptr, nullptr, Sb[0], Sb[1], NN, HH, HH);
    // 4a. S2^T bf16
    transpose_f2b<<<dim3(HH / 32, NN / 32, 2), 256, 0, stream>>>(
        Sb[0], Sb[1], ST[0], ST[1], NN, HH);
    // 4b. X2 = lrelu(adj @ S2 + b2)  (bf16 MFMA)
    gemm_mfma_adj<<<dim3(HH / 64, NN / 64, 2), 256, 0, stream>>>(
        adj[0], adj[1], ST[0], ST[1], g2b[0], g2b[1], Xb[0], Xb[1]);
    // 5. H = X2 @ gat_W           [4096,256]x[256,128]  (fp32 VALU) -> Sb
    gemm_batch2<false><<<dim3(FF / 64, NN / 64, 2), 256, 0, stream>>>(
        Xb[0], Xb[1], gaW[0], gaW[1], nullptr, nullptr, Sb[0], Sb[1], NN, FF, HH);
    // 5b. H^T bf16
    transpose_f2b<<<dim3(FF / 32, NN / 32, 2), 256, 0, stream>>>(
        Sb[0], Sb[1], HT[0], HT[1], NN, FF);
    // 6. s1/s2
    s12_kernel<<<dim3(NN, 2), 64, 0, stream>>>(
        Sb[0], Sb[1], gaA[0], gaA[1], s1p[0], s1p[1], s2p[0], s2p[1]);
    // 7. O = lrelu(softmax(mask(e)) @ H)  (MFMA flash) -> Xb
    gat_mfma<<<dim3(NN / 32, 2), 256, 0, stream>>>(
        adj[0], adj[1], HT[0], HT[1], s1p[0], s1p[1], s2p[0], s2p[1], Xb[0], Xb[1]);
    // 8. PoE + predictors + softmax -> out [4096,15]
    final_fused<<<NN, 128, 0, stream>>>(
        Xb[0], Xb[1], mask,
        jpW1, jpb1, jpW2, jpb2,
        sW1[0], sb1[0], sW2[0], sb2[0],
        sW1[1], sb1[1], sW2[1], sb2[1],
        out);
}

// Round 4
// 280.772 us; speedup vs baseline: 3.6133x; 1.1610x over previous
//
#include <hip/hip_runtime.h>
#include <math.h>

// Problem dims (fixed)
#define NN 4096     // nodes
#define DD 400      // input feature dim
#define HH 256      // GCN hidden
#define FF 128      // GAT out dim
#define PH 128      // predictor hidden
#define YY 5        // classes

typedef float f32x4v __attribute__((ext_vector_type(4)));
typedef short bf16x8 __attribute__((ext_vector_type(8)));

__device__ __forceinline__ float lrelu(float v) { return v >= 0.f ? v : 0.25f * v; }
// fp32 -> bf16 round-to-nearest-even
__device__ __forceinline__ short f2b(float f) {
    unsigned u = __float_as_uint(f);
    unsigned r = (u + 0x7fffu + ((u >> 16) & 1u)) >> 16;
    return (short)r;
}

// ---------------------------------------------------------------------------
// fp32 tiled GEMM (steps 1,3,5 — small K, cheap).
// ---------------------------------------------------------------------------
template<bool FUSE>
__global__ __launch_bounds__(256) void gemm_batch2(
    const float* __restrict__ A0, const float* __restrict__ A1,
    const float* __restrict__ B0, const float* __restrict__ B1,
    const float* __restrict__ bias0, const float* __restrict__ bias1,
    float* __restrict__ C0, float* __restrict__ C1,
    int M, int N, int K)
{
    const float* A   = blockIdx.z ? A1 : A0;
    const float* B   = blockIdx.z ? B1 : B0;
    const float* bias = blockIdx.z ? bias1 : bias0;
    float* C         = blockIdx.z ? C1 : C0;

    __shared__ float As[16][68];
    __shared__ float Bs[16][68];

    const int tid = threadIdx.x;
    const int tx = tid & 15, ty = tid >> 4;
    const int m0 = blockIdx.y * 64, n0 = blockIdx.x * 64;

    float acc[4][4] = {{0.f}};

    for (int k0 = 0; k0 < K; k0 += 16) {
        #pragma unroll
        for (int i = 0; i < 4; ++i) {
            int idx = tid + i * 256;
            int am = idx >> 4, ak = idx & 15;
            As[ak][am] = A[(size_t)(m0 + am) * K + (k0 + ak)];
        }
        #pragma unroll
        for (int i = 0; i < 4; ++i) {
            int idx = tid + i * 256;
            int bk = idx >> 6, bn = idx & 63;
            Bs[bk][bn] = B[(size_t)(k0 + bk) * N + (n0 + bn)];
        }
        __syncthreads();
        #pragma unroll
        for (int k = 0; k < 16; ++k) {
            float a4[4], b4[4];
            *(float4*)a4 = *(const float4*)&As[k][ty * 4];
            *(float4*)b4 = *(const float4*)&Bs[k][tx * 4];
            #pragma unroll
            for (int i = 0; i < 4; ++i)
                #pragma unroll
                for (int j = 0; j < 4; ++j)
                    acc[i][j] = fmaf(a4[i], b4[j], acc[i][j]);
        }
        __syncthreads();
    }

    #pragma unroll
    for (int i = 0; i < 4; ++i) {
        int row = m0 + ty * 4 + i;
        #pragma unroll
        for (int j = 0; j < 4; ++j) {
            int col = n0 + tx * 4 + j;
            float v = acc[i][j];
            if (FUSE) { v += bias[col]; v = lrelu(v); }
            C[(size_t)row * N + col] = v;
        }
    }
}

// ---------------------------------------------------------------------------
// Transpose + fp32->bf16: in [R,C] f32 -> out [C,R] bf16. grid (C/32, R/32, 2)
// ---------------------------------------------------------------------------
__global__ __launch_bounds__(256) void transpose_f2b(
    const float* __restrict__ in0, const float* __restrict__ in1,
    short* __restrict__ out0, short* __restrict__ out1, int R, int C)
{
    const float* in = blockIdx.z ? in1 : in0;
    short* out      = blockIdx.z ? out1 : out0;
    __shared__ float T[32][33];
    const int r0 = blockIdx.y * 32, c0 = blockIdx.x * 32;
    const int t = threadIdx.x, r = t >> 5, c = t & 31;
    #pragma unroll
    for (int p = 0; p < 4; ++p)
        T[r + p * 8][c] = in[(size_t)(r0 + r + p * 8) * C + c0 + c];
    __syncthreads();
    #pragma unroll
    for (int p = 0; p < 4; ++p)
        out[(size_t)(c0 + r + p * 8) * R + r0 + c] = f2b(T[c][r + p * 8]);
}

// ---------------------------------------------------------------------------
// bf16 MFMA GEMM for X = lrelu(adj @ S + bias)  (steps 2,4)
// Full-N tile: BM=32, BN=256(all), BK=128 -> adj fetched exactly ONCE.
// 512 thr (8 waves 2Mx4N, each 16x64, acc=4 frags). BT (S^T bf16 [256,4096])
// is L2-resident. Two-deep register prefetch (P0/P1), LDS rows padded to
// 136 shorts (272B == 4 banks mod 32 -> 2-way aliasing, free).
// Grid: (NN/32, 2) = 256 blocks = 1/CU.
// ---------------------------------------------------------------------------
struct PrefG {
    float4 a0, a1;                               // adj 8 fp32
    bf16x8 b0, b1, b2, b3, b4, b5, b6, b7;       // BT 8 rows x 8 bf16
};

__global__ __launch_bounds__(512) void gemm_mfma_adj(
    const float* __restrict__ A0p, const float* __restrict__ A1p,
    const short* __restrict__ BT0, const short* __restrict__ BT1,
    const float* __restrict__ bias0, const float* __restrict__ bias1,
    float* __restrict__ C0, float* __restrict__ C1)
{
    const float* A    = blockIdx.y ? A1p : A0p;
    const short* BT   = blockIdx.y ? BT1 : BT0;
    const float* bias = blockIdx.y ? bias1 : bias0;
    float* C          = blockIdx.y ? C1 : C0;

    __shared__ short As[32 * 136];    //  8.5 KB
    __shared__ short Bs[256 * 136];   // 68.0 KB

    const int tid = threadIdx.x;
    const int m0 = blockIdx.x * 32;
    const int w = tid >> 6, l = tid & 63;
    const int wr = w >> 2, wc = w & 3;           // 2 x 4 wave grid
    const int fr = l & 15, fq = l >> 4;

    // staging coords: adj row/k (8 floats per thread), BT row/k (16B x 8 rows)
    const int ar = tid >> 4, ak = (tid & 15) * 8;
    const int br = tid >> 4, bk = (tid & 15) * 8;

    const float* Ap = A  + (size_t)(m0 + ar) * 4096 + ak;
    const short* Bp = BT + (size_t)br * 4096 + bk;

    short* As_w = As + ar * 136 + ak;
    short* Bs_w = Bs + br * 136 + bk;
    const short* Af = As + (wr * 16 + fr) * 136 + fq * 8;
    const short* Bf = Bs + (wc * 64 + fr) * 136 + fq * 8;

    f32x4v acc0 = {0.f,0.f,0.f,0.f}, acc1 = {0.f,0.f,0.f,0.f};
    f32x4v acc2 = {0.f,0.f,0.f,0.f}, acc3 = {0.f,0.f,0.f,0.f};

    PrefG P0, P1;

    auto loadr = [&](PrefG& P, int t) {
        const int kk = t * 128;
        P.a0 = *(const float4*)(Ap + kk);
        P.a1 = *(const float4*)(Ap + kk + 4);
        P.b0 = *(const bf16x8*)(Bp + kk);
        P.b1 = *(const bf16x8*)(Bp + kk +  32 * 4096);
        P.b2 = *(const bf16x8*)(Bp + kk +  64 * 4096);
        P.b3 = *(const bf16x8*)(Bp + kk +  96 * 4096);
        P.b4 = *(const bf16x8*)(Bp + kk + 128 * 4096);
        P.b5 = *(const bf16x8*)(Bp + kk + 160 * 4096);
        P.b6 = *(const bf16x8*)(Bp + kk + 192 * 4096);
        P.b7 = *(const bf16x8*)(Bp + kk + 224 * 4096);
    };

    auto stage = [&](PrefG& P) {
        bf16x8 av;
        av[0] = f2b(P.a0.x); av[1] = f2b(P.a0.y); av[2] = f2b(P.a0.z); av[3] = f2b(P.a0.w);
        av[4] = f2b(P.a1.x); av[5] = f2b(P.a1.y); av[6] = f2b(P.a1.z); av[7] = f2b(P.a1.w);
        *(bf16x8*)As_w = av;
        *(bf16x8*)(Bs_w + 0 * 32 * 136) = P.b0;
        *(bf16x8*)(Bs_w + 1 * 32 * 136) = P.b1;
        *(bf16x8*)(Bs_w + 2 * 32 * 136) = P.b2;
        *(bf16x8*)(Bs_w + 3 * 32 * 136) = P.b3;
        *(bf16x8*)(Bs_w + 4 * 32 * 136) = P.b4;
        *(bf16x8*)(Bs_w + 5 * 32 * 136) = P.b5;
        *(bf16x8*)(Bs_w + 6 * 32 * 136) = P.b6;
        *(bf16x8*)(Bs_w + 7 * 32 * 136) = P.b7;
    };

    auto mfma16 = [&]() {
        #pragma unroll
        for (int h = 0; h < 4; ++h) {            // 4 k-halves of 32
            bf16x8 Ah  = *(const bf16x8*)(Af + h * 32);
            bf16x8 Bv0 = *(const bf16x8*)(Bf + h * 32);
            bf16x8 Bv1 = *(const bf16x8*)(Bf + 16 * 136 + h * 32);
            bf16x8 Bv2 = *(const bf16x8*)(Bf + 32 * 136 + h * 32);
            bf16x8 Bv3 = *(const bf16x8*)(Bf + 48 * 136 + h * 32);
            acc0 = __builtin_amdgcn_mfma_f32_16x16x32_bf16(Ah, Bv0, acc0, 0, 0, 0);
            acc1 = __builtin_amdgcn_mfma_f32_16x16x32_bf16(Ah, Bv1, acc1, 0, 0, 0);
            acc2 = __builtin_amdgcn_mfma_f32_16x16x32_bf16(Ah, Bv2, acc2, 0, 0, 0);
            acc3 = __builtin_amdgcn_mfma_f32_16x16x32_bf16(Ah, Bv3, acc3, 0, 0, 0);
        }
    };

    loadr(P0, 0);
    loadr(P1, 1);
    for (int it = 0; it < 16; ++it) {
        stage(P0);
        if (it < 15) loadr(P0, 2 * it + 2);
        __syncthreads();
        mfma16();
        __syncthreads();
        stage(P1);
        if (it < 15) loadr(P1, 2 * it + 3);
        __syncthreads();
        mfma16();
        __syncthreads();
    }

    const int crow = m0 + wr * 16 + fq * 4;
    const int ccol = wc * 64 + fr;
    const float bv0 = bias[ccol], bv1 = bias[ccol + 16];
    const float bv2 = bias[ccol + 32], bv3 = bias[ccol + 48];
    #pragma unroll
    for (int q = 0; q < 4; ++q) {
        float* Cr = C + (size_t)(crow + q) * HH;
        Cr[ccol]      = lrelu(acc0[q] + bv0);
        Cr[ccol + 16] = lrelu(acc1[q] + bv1);
        Cr[ccol + 32] = lrelu(acc2[q] + bv2);
        Cr[ccol + 48] = lrelu(acc3[q] + bv3);
    }
}

// ---------------------------------------------------------------------------
// s1[i] = H[i,:] . a[0:128] ; s2[i] = H[i,:] . a[128:256]
// ---------------------------------------------------------------------------
__global__ void s12_kernel(
    const float* __restrict__ H0, const float* __restrict__ H1,
    const float* __restrict__ a0, const float* __restrict__ a1,
    float* __restrict__ s1_0, float* __restrict__ s1_1,
    float* __restrict__ s2_0, float* __restrict__ s2_1)
{
    const int z = blockIdx.y;
    const float* H = z ? H1 : H0;
    const float* a = z ? a1 : a0;
    float* s1 = z ? s1_1 : s1_0;
    float* s2 = z ? s2_1 : s2_0;

    const int i = blockIdx.x, t = threadIdx.x;   // 64 threads
    float h0 = H[(size_t)i * FF + t];
    float h1 = H[(size_t)i * FF + 64 + t];
    float v1 = h0 * a[t] + h1 * a[64 + t];
    float v2 = h0 * a[128 + t] + h1 * a[192 + t];
    #pragma unroll
    for (int off = 32; off > 0; off >>= 1) {
        v1 += __shfl_down(v1, off);
        v2 += __shfl_down(v2, off);
    }
    if (t == 0) { s1[i] = v1; s2[i] = v2; }
}

// ---------------------------------------------------------------------------
// MFMA flash-GAT: O = lrelu(softmax_row(mask(lrelu(s1_i+s2_j))) @ H)
// (unchanged from round 3 — passed)
// ---------------------------------------------------------------------------
struct Pref {
    float4 a0, a1, s0, s1;
    bf16x8 h0, h1, h2, h3;
};

__global__ __launch_bounds__(256) void gat_mfma(
    const float* __restrict__ adj0, const float* __restrict__ adj1,
    const short* __restrict__ HT0, const short* __restrict__ HT1,
    const float* __restrict__ s1_0, const float* __restrict__ s1_1,
    const float* __restrict__ s2_0, const float* __restrict__ s2_1,
    float* __restrict__ O0, float* __restrict__ O1)
{
    const int z = blockIdx.y;
    const float* adjp = z ? adj1 : adj0;
    const short* HTp  = z ? HT1 : HT0;
    const float* s1v  = z ? s1_1 : s1_0;
    const float* s2v  = z ? s2_1 : s2_0;
    float* Op         = z ? O1 : O0;

    __shared__ short Pl[32 * 88];    // P tile (bf16), padded rows
    __shared__ short HTl[128 * 88];  // H^T tile (bf16), padded rows
    __shared__ float scl[32];
    __shared__ float lrw[32];

    const int tid = threadIdx.x;
    const int i0 = blockIdx.x * 32;
    const int r = tid >> 3, cg = tid & 7, c0 = cg * 8;
    const int l = tid & 63, w = tid >> 6;
    const int fr = l & 15, fq = l >> 4;

    const float s1r = s1v[i0 + r];
    float mrun = -3.0e38f, lsum = 0.f;
    f32x4v acc00 = {0.f,0.f,0.f,0.f}, acc01 = {0.f,0.f,0.f,0.f};
    f32x4v acc10 = {0.f,0.f,0.f,0.f}, acc11 = {0.f,0.f,0.f,0.f};

    const float* adjrow = adjp + (size_t)(i0 + r) * 4096 + c0;
    const short* htrow  = HTp + (size_t)r * 4096 + c0;

    Pref PA, PB;

    auto loadr = [&](Pref& P, int J) {
        P.a0 = *(const float4*)(adjrow + J);
        P.a1 = *(const float4*)(adjrow + J + 4);
        P.s0 = *(const float4*)(s2v + J + c0);
        P.s1 = *(const float4*)(s2v + J + c0 + 4);
        P.h0 = *(const bf16x8*)(htrow + J);
        P.h1 = *(const bf16x8*)(htrow + J + 32 * 4096);
        P.h2 = *(const bf16x8*)(htrow + J + 64 * 4096);
        P.h3 = *(const bf16x8*)(htrow + J + 96 * 4096);
    };

    auto process = [&](Pref& P) {
        float e0 = (P.a0.x > 0.f) ? lrelu(s1r + P.s0.x) : -1e12f;
        float e1 = (P.a0.y > 0.f) ? lrelu(s1r + P.s0.y) : -1e12f;
        float e2 = (P.a0.z > 0.f) ? lrelu(s1r + P.s0.z) : -1e12f;
        float e3 = (P.a0.w > 0.f) ? lrelu(s1r + P.s0.w) : -1e12f;
        float e4 = (P.a1.x > 0.f) ? lrelu(s1r + P.s1.x) : -1e12f;
        float e5 = (P.a1.y > 0.f) ? lrelu(s1r + P.s1.y) : -1e12f;
        float e6 = (P.a1.z > 0.f) ? lrelu(s1r + P.s1.z) : -1e12f;
        float e7 = (P.a1.w > 0.f) ? lrelu(s1r + P.s1.w) : -1e12f;
        float lm = fmaxf(fmaxf(fmaxf(e0, e1), fmaxf(e2, e3)),
                         fmaxf(fmaxf(e4, e5), fmaxf(e6, e7)));
        lm = fmaxf(lm, __shfl_xor(lm, 1));
        lm = fmaxf(lm, __shfl_xor(lm, 2));
        lm = fmaxf(lm, __shfl_xor(lm, 4));
        float mnew = fmaxf(mrun, lm);
        float sc = __expf(mrun - mnew);
        float w0 = __expf(e0 - mnew), w1 = __expf(e1 - mnew);
        float w2 = __expf(e2 - mnew), w3 = __expf(e3 - mnew);
        float w4 = __expf(e4 - mnew), w5 = __expf(e5 - mnew);
        float w6 = __expf(e6 - mnew), w7 = __expf(e7 - mnew);
        float wsm = ((w0 + w1) + (w2 + w3)) + ((w4 + w5) + (w6 + w7));
        wsm += __shfl_xor(wsm, 1); wsm += __shfl_xor(wsm, 2); wsm += __shfl_xor(wsm, 4);
        lsum = lsum * sc + wsm; mrun = mnew;
        __syncthreads();   // previous MFMA reads done before overwriting tiles
        bf16x8 wv;
        wv[0] = f2b(w0); wv[1] = f2b(w1); wv[2] = f2b(w2); wv[3] = f2b(w3);
        wv[4] = f2b(w4); wv[5] = f2b(w5); wv[6] = f2b(w6); wv[7] = f2b(w7);
        *(bf16x8*)(Pl + r * 88 + c0) = wv;
        *(bf16x8*)(HTl + (r +  0) * 88 + c0) = P.h0;
        *(bf16x8*)(HTl + (r + 32) * 88 + c0) = P.h1;
        *(bf16x8*)(HTl + (r + 64) * 88 + c0) = P.h2;
        *(bf16x8*)(HTl + (r + 96) * 88 + c0) = P.h3;
        if (cg == 0) scl[r] = sc;
        __syncthreads();
        float q0 = scl[fq * 4 + 0], q1 = scl[fq * 4 + 1];
        float q2 = scl[fq * 4 + 2], q3 = scl[fq * 4 + 3];
        float p0 = scl[16 + fq * 4 + 0], p1 = scl[16 + fq * 4 + 1];
        float p2 = scl[16 + fq * 4 + 2], p3 = scl[16 + fq * 4 + 3];
        acc00[0] *= q0; acc00[1] *= q1; acc00[2] *= q2; acc00[3] *= q3;
        acc01[0] *= q0; acc01[1] *= q1; acc01[2] *= q2; acc01[3] *= q3;
        acc10[0] *= p0; acc10[1] *= p1; acc10[2] *= p2; acc10[3] *= p3;
        acc11[0] *= p0; acc11[1] *= p1; acc11[2] *= p2; acc11[3] *= p3;
        const short* Af = Pl + fr * 88 + fq * 8;
        const short* Bf = HTl + (w * 32 + fr) * 88 + fq * 8;
        bf16x8 A00 = *(const bf16x8*)(Af);
        bf16x8 A10 = *(const bf16x8*)(Af + 16 * 88);
        bf16x8 A01 = *(const bf16x8*)(Af + 32);
        bf16x8 A11 = *(const bf16x8*)(Af + 16 * 88 + 32);
        bf16x8 B00 = *(const bf16x8*)(Bf);
        bf16x8 B10 = *(const bf16x8*)(Bf + 16 * 88);
        bf16x8 B01 = *(const bf16x8*)(Bf + 32);
        bf16x8 B11 = *(const bf16x8*)(Bf + 16 * 88 + 32);
        acc00 = __builtin_amdgcn_mfma_f32_16x16x32_bf16(A00, B00, acc00, 0, 0, 0);
        acc01 = __builtin_amdgcn_mfma_f32_16x16x32_bf16(A00, B10, acc01, 0, 0, 0);
        acc10 = __builtin_amdgcn_mfma_f32_16x16x32_bf16(A10, B00, acc10, 0, 0, 0);
        acc11 = __builtin_amdgcn_mfma_f32_16x16x32_bf16(A10, B10, acc11, 0, 0, 0);
        acc00 = __builtin_amdgcn_mfma_f32_16x16x32_bf16(A01, B01, acc00, 0, 0, 0);
        acc01 = __builtin_amdgcn_mfma_f32_16x16x32_bf16(A01, B11, acc01, 0, 0, 0);
        acc10 = __builtin_amdgcn_mfma_f32_16x16x32_bf16(A11, B01, acc10, 0, 0, 0);
        acc11 = __builtin_amdgcn_mfma_f32_16x16x32_bf16(A11, B11, acc11, 0, 0, 0);
    };

    loadr(PA, 0);
    for (int it = 0; it < 32; ++it) {
        const int j0 = it * 128;
        loadr(PB, j0 + 64);
        process(PA);
        if (it < 31) loadr(PA, j0 + 128);
        process(PB);
    }

    if (cg == 0) lrw[r] = lsum;
    __syncthreads();
    const int col = w * 32 + fr;
    #pragma unroll
    for (int q = 0; q < 4; ++q) {
        const int rl0 = fq * 4 + q, rl1 = 16 + fq * 4 + q;
        Op[(size_t)(i0 + rl0) * FF + col]      = lrelu(acc00[q] / lrw[rl0]);
        Op[(size_t)(i0 + rl0) * FF + col + 16] = lrelu(acc01[q] / lrw[rl0]);
        Op[(size_t)(i0 + rl1) * FF + col]      = lrelu(acc10[q] / lrw[rl1]);
        Op[(size_t)(i0 + rl1) * FF + col + 16] = lrelu(acc11[q] / lrw[rl1]);
    }
}

// ---------------------------------------------------------------------------
// PoE + 3 predictors + softmax (unchanged)
// ---------------------------------------------------------------------------
__global__ __launch_bounds__(128) void final_fused(
    const float* __restrict__ O0, const float* __restrict__ O1,
    const float* __restrict__ mask,
    const float* __restrict__ jpW1, const float* __restrict__ jpb1,
    const float* __restrict__ jpW2, const float* __restrict__ jpb2,
    const float* __restrict__ sW1_0, const float* __restrict__ sb1_0,
    const float* __restrict__ sW2_0, const float* __restrict__ sb2_0,
    const float* __restrict__ sW1_1, const float* __restrict__ sb1_1,
    const float* __restrict__ sW2_1, const float* __restrict__ sb2_1,
    float* __restrict__ out)
{
    __shared__ float zbuf[3][64];
    __shared__ float hbuf[3][128];
    __shared__ float lg[16];

    const int i = blockIdx.x, t = threadIdx.x;

    if (t < 64) {
        float mu0 = O0[(size_t)i * FF + t];
        float lv0 = O0[(size_t)i * FF + 64 + t];
        float mu1 = O1[(size_t)i * FF + t];
        float lv1 = O1[(size_t)i * FF + 64 + t];
        float p0 = 1.f / (__expf(lv0) + 1e-8f);
        float p1 = 1.f / (__expf(lv1) + 1e-8f);
        float mk0 = mask[(size_t)i * 2 + 0];
        float mk1 = mask[(size_t)i * 2 + 1];
        float tmp = 1.f + mk0 * p0 + mk1 * p1;
        float jv = 1.f / (tmp + 1e-8f);
        zbuf[0][t] = jv * (mk0 * p0 * mu0 + mk1 * p1 * mu1);
        zbuf[1][t] = mu0;
        zbuf[2][t] = mu1;
    }
    __syncthreads();

    {
        float s0 = jpb1[t], s1 = sb1_0[t], s2 = sb1_1[t];
        for (int k = 0; k < 64; ++k) {
            float z0 = zbuf[0][k], z1 = zbuf[1][k], z2 = zbuf[2][k];
            s0 = fmaf(z0, jpW1[k * PH + t], s0);
            s1 = fmaf(z1, sW1_0[k * PH + t], s1);
            s2 = fmaf(z2, sW1_1[k * PH + t], s2);
        }
        hbuf[0][t] = lrelu(s0);
        hbuf[1][t] = lrelu(s1);
        hbuf[2][t] = lrelu(s2);
    }
    __syncthreads();

    if (t < 15) {
        int p = t / 5, c = t % 5;
        const float* W2 = (p == 0) ? jpW2 : (p == 1 ? sW2_0 : sW2_1);
        const float* b2 = (p == 0) ? jpb2 : (p == 1 ? sb2_0 : sb2_1);
        float s = b2[c];
        for (int k = 0; k < 128; ++k) s = fmaf(hbuf[p][k], W2[k * YY + c], s);
        lg[t] = s;
    }
    __syncthreads();

    if (t < 3) {
        float mx = -3e38f;
        #pragma unroll
        for (int c = 0; c < 5; ++c) mx = fmaxf(mx, lg[t * 5 + c]);
        float ex[5], sum = 0.f;
        #pragma unroll
        for (int c = 0; c < 5; ++c) { ex[c] = __expf(lg[t * 5 + c] - mx); sum += ex[c]; }
        #pragma unroll
        for (int c = 0; c < 5; ++c)
            out[(size_t)i * 15 + t * 5 + c] = ex[c] / sum;
    }
}

// ---------------------------------------------------------------------------
extern "C" void kernel_launch(void* const* d_in, const int* in_sizes, int n_in,
                              void* d_out, int out_size, void* d_ws, size_t ws_size,
                              hipStream_t stream)
{
    const float* x[2]   = {(const float*)d_in[0],  (const float*)d_in[12]};
    const float* adj[2] = {(const float*)d_in[1],  (const float*)d_in[13]};
    const float* g1W[2] = {(const float*)d_in[2],  (const float*)d_in[14]};
    const float* g1b[2] = {(const float*)d_in[3],  (const float*)d_in[15]};
    const float* g2W[2] = {(const float*)d_in[4],  (const float*)d_in[16]};
    const float* g2b[2] = {(const float*)d_in[5],  (const float*)d_in[17]};
    const float* gaW[2] = {(const float*)d_in[6],  (const float*)d_in[18]};
    const float* gaA[2] = {(const float*)d_in[7],  (const float*)d_in[19]};
    const float* sW1[2] = {(const float*)d_in[8],  (const float*)d_in[20]};
    const float* sb1[2] = {(const float*)d_in[9],  (const float*)d_in[21]};
    const float* sW2[2] = {(const float*)d_in[10], (const float*)d_in[22]};
    const float* sb2[2] = {(const float*)d_in[11], (const float*)d_in[23]};
    const float* mask   = (const float*)d_in[24];
    const float* jpW1   = (const float*)d_in[25];
    const float* jpb1   = (const float*)d_in[26];
    const float* jpW2   = (const float*)d_in[27];
    const float* jpb2   = (const float*)d_in[28];
    float* out = (float*)d_out;

    float* ws = (float*)d_ws;
    const size_t NH = (size_t)NN * HH;   // 1,048,576
    const size_t NF = (size_t)NN * FF;   //   524,288
    float* Sb[2] = {ws,          ws + NH};        // S / S2 / H (fp32)
    float* Xb[2] = {ws + 2 * NH, ws + 3 * NH};    // X1 / X2 / O (fp32)
    short* STb   = (short*)(ws + 4 * NH);
    short* ST[2] = {STb, STb + NH};               // S^T bf16 [256,4096]
    short* HT[2] = {STb + 2 * NH, STb + 2 * NH + NF}; // H^T bf16 [128,4096]
    float* sv    = ws + 5 * NH + NF;
    float* s1p[2] = {sv,            sv + NN};
    float* s2p[2] = {sv + 2 * NN,   sv + 3 * NN};
    // total: 5*NH + NF + 4*NN floats ~ 23.1 MB

    // 1. S = x @ gc1_W            [4096,400]x[400,256]  (fp32 VALU)
    gemm_batch2<false><<<dim3(HH / 64, NN / 64, 2), 256, 0, stream>>>(
        x[0], x[1], g1W[0], g1W[1], nullptr, nullptr, Sb[0], Sb[1], NN, HH, DD);
    // 2a. S^T bf16
    transpose_f2b<<<dim3(HH / 32, NN / 32, 2), 256, 0, stream>>>(
        Sb[0], Sb[1], ST[0], ST[1], NN, HH);
    // 2b. X1 = lrelu(adj @ S + b1)   (bf16 MFMA, full-N tile)
    gemm_mfma_adj<<<dim3(NN / 32, 2), 512, 0, stream>>>(
        adj[0], adj[1], ST[0], ST[1], g1b[0], g1b[1], Xb[0], Xb[1]);
    // 3. S2 = X1 @ gc2_W          [4096,256]x[256,256]  (fp32 VALU)
    gemm_batch2<false><<<dim3(HH / 64, NN / 64, 2), 256, 0, stream>>>(
        Xb[0], Xb[1], g2W[0], g2W[1], nullptr, nullptr, Sb[0], Sb[1], NN, HH, HH);
    // 4a. S2^T bf16
    transpose_f2b<<<dim3(HH / 32, NN / 32, 2), 256, 0, stream>>>(
        Sb[0], Sb[1], ST[0], ST[1], NN, HH);
    // 4b. X2 = lrelu(adj @ S2 + b2)  (bf16 MFMA, full-N tile)
    gemm_mfma_adj<<<dim3(NN / 32, 2), 512, 0, stream>>>(
        adj[0], adj[1], ST[0], ST[1], g2b[0], g2b[1], Xb[0], Xb[1]);
    // 5. H = X2 @ gat_W           [4096,256]x[256,128]  (fp32 VALU) -> Sb
    gemm_batch2<false><<<dim3(FF / 64, NN / 64, 2), 256, 0, stream>>>(
        Xb[0], Xb[1], gaW[0], gaW[1], nullptr, nullptr, Sb[0], Sb[1], NN, FF, HH);
    // 5b. H^T bf16
    transpose_f2b<<<dim3(FF / 32, NN / 32, 2), 256, 0, stream>>>(
        Sb[0], Sb[1], HT[0], HT[1], NN, FF);
    // 6. s1/s2
    s12_kernel<<<dim3(NN, 2), 64, 0, stream>>>(
        Sb[0], Sb[1], gaA[0], gaA[1], s1p[0], s1p[1], s2p[0], s2p[1]);
    // 7. O = lrelu(softmax(mask(e)) @ H)  (MFMA flash) -> Xb
    gat_mfma<<<dim3(NN / 32, 2), 256, 0, stream>>>(
        adj[0], adj[1], HT[0], HT[1], s1p[0], s1p[1], s2p[0], s2p[1], Xb[0], Xb[1]);
    // 8. PoE + predictors + softmax -> out [4096,15]
    final_fused<<<NN, 128, 0, stream>>>(
        Xb[0], Xb[1], mask,
        jpW1, jpb1, jpW2, jpb2,
        sW1[0], sb1[0], sW2[0], sb2[0],
        sW1[1], sb1[1], sW2[1], sb2[1],
        out);
}

// Round 5
// 253.818 us; speedup vs baseline: 3.9970x; 1.1062x over previous
//
#include <hip/hip_runtime.h>
#include <math.h>

// Problem dims (fixed)
#define NN 4096     // nodes
#define DD 400      // input feature dim
#define HH 256      // GCN hidden
#define FF 128      // GAT out dim
#define PH 128      // predictor hidden
#define YY 5        // classes

typedef float f32x4v __attribute__((ext_vector_type(4)));
typedef short bf16x8 __attribute__((ext_vector_type(8)));
typedef short bf16x4 __attribute__((ext_vector_type(4)));

__device__ __forceinline__ float lrelu(float v) { return v >= 0.f ? v : 0.25f * v; }
// fp32 -> bf16 round-to-nearest-even
__device__ __forceinline__ short f2b(float f) {
    unsigned u = __float_as_uint(f);
    unsigned r = (u + 0x7fffu + ((u >> 16) & 1u)) >> 16;
    return (short)r;
}

// ---------------------------------------------------------------------------
// Weight prep: in [R,C] fp32 -> out [C,RP] bf16 (transpose, zero-pad rows>=R)
// grid (C/32, RP/32, 2), 256 thr
// ---------------------------------------------------------------------------
__global__ __launch_bounds__(256) void transpose_f2b_pad(
    const float* __restrict__ in0, const float* __restrict__ in1,
    short* __restrict__ out0, short* __restrict__ out1, int R, int C, int RP)
{
    const float* in = blockIdx.z ? in1 : in0;
    short* out      = blockIdx.z ? out1 : out0;
    __shared__ float T[32][33];
    const int r0 = blockIdx.y * 32, c0 = blockIdx.x * 32;
    const int t = threadIdx.x, r = t >> 5, c = t & 31;
    #pragma unroll
    for (int p = 0; p < 4; ++p) {
        int rr = r0 + r + p * 8;
        T[r + p * 8][c] = (rr < R) ? in[(size_t)rr * C + c0 + c] : 0.f;
    }
    __syncthreads();
    #pragma unroll
    for (int p = 0; p < 4; ++p)
        out[(size_t)(c0 + r + p * 8) * RP + r0 + c] = f2b(T[c][r + p * 8]);
}

// ---------------------------------------------------------------------------
// Generic bf16 MFMA GEMM (steps 1,3,5): C[M=4096,N] = A[M,K] @ B[K,N]
// A fp32 (inline cvt) or bf16; BT = B^T bf16 [N, ldb] zero-padded to KSTEPS*64.
// Writes CT bf16 [N,4096] (=C^T) and/or C fp32 [4096,N].
// BM=BN=64, BK=64, 256 thr (4 waves 2x2, each 32x32).
// ---------------------------------------------------------------------------
struct PrefMM {
    float4 a0, a1, a2, a3;    // A fp32 path
    bf16x8 ab0, ab1;          // A bf16 path
    bf16x8 b0, b1;            // B
};

template<bool ABF16, bool WC, bool WCT, int KSTEPS>
__global__ __launch_bounds__(256) void gemm_mfma_gen(
    const void* __restrict__ A0, const void* __restrict__ A1,
    const short* __restrict__ BT0, const short* __restrict__ BT1,
    float* __restrict__ C0, float* __restrict__ C1,
    short* __restrict__ CT0, short* __restrict__ CT1,
    int lda, int ldb, int N, int kvalid)
{
    const void* A   = blockIdx.z ? A1 : A0;
    const short* BT = blockIdx.z ? BT1 : BT0;
    float* C        = blockIdx.z ? C1 : C0;
    short* CT       = blockIdx.z ? CT1 : CT0;

    __shared__ short As[64 * 88];
    __shared__ short Bs[64 * 88];

    const int tid = threadIdx.x;
    const int m0 = blockIdx.y * 64, n0 = blockIdx.x * 64;
    const int l = tid & 63, w = tid >> 6;
    const int wr = w >> 1, wc = w & 1;
    const int fr = l & 15, fq = l >> 4;
    const int sr = tid >> 2, sk = (tid & 3) * 16;

    const float* Apf = (const float*)A + (size_t)(m0 + sr) * lda + sk;
    const short* Apb = (const short*)A + (size_t)(m0 + sr) * lda + sk;
    const short* Bp  = BT + (size_t)(n0 + sr) * ldb + sk;

    short* As_w = As + sr * 88 + sk;
    short* Bs_w = Bs + sr * 88 + sk;
    const short* Af = As + (wr * 32 + fr) * 88 + fq * 8;
    const short* Bf = Bs + (wc * 32 + fr) * 88 + fq * 8;

    f32x4v acc00 = {0.f,0.f,0.f,0.f}, acc01 = {0.f,0.f,0.f,0.f};
    f32x4v acc10 = {0.f,0.f,0.f,0.f}, acc11 = {0.f,0.f,0.f,0.f};

    PrefMM P[2];

    auto loadr = [&](PrefMM& Pr, int t) {
        const int kk = t * 64;
        const bool valid = (kk + sk) < kvalid;
        if (ABF16) {
            if (valid) {
                Pr.ab0 = *(const bf16x8*)(Apb + kk);
                Pr.ab1 = *(const bf16x8*)(Apb + kk + 8);
            } else {
                Pr.ab0 = (bf16x8)0; Pr.ab1 = (bf16x8)0;
            }
        } else {
            if (valid) {
                Pr.a0 = *(const float4*)(Apf + kk);
                Pr.a1 = *(const float4*)(Apf + kk + 4);
                Pr.a2 = *(const float4*)(Apf + kk + 8);
                Pr.a3 = *(const float4*)(Apf + kk + 12);
            } else {
                Pr.a0 = Pr.a1 = Pr.a2 = Pr.a3 = make_float4(0.f, 0.f, 0.f, 0.f);
            }
        }
        Pr.b0 = *(const bf16x8*)(Bp + kk);
        Pr.b1 = *(const bf16x8*)(Bp + kk + 8);
    };

    auto stage = [&](PrefMM& Pr) {
        if (ABF16) {
            *(bf16x8*)(As_w)     = Pr.ab0;
            *(bf16x8*)(As_w + 8) = Pr.ab1;
        } else {
            bf16x8 v0, v1;
            v0[0] = f2b(Pr.a0.x); v0[1] = f2b(Pr.a0.y); v0[2] = f2b(Pr.a0.z); v0[3] = f2b(Pr.a0.w);
            v0[4] = f2b(Pr.a1.x); v0[5] = f2b(Pr.a1.y); v0[6] = f2b(Pr.a1.z); v0[7] = f2b(Pr.a1.w);
            v1[0] = f2b(Pr.a2.x); v1[1] = f2b(Pr.a2.y); v1[2] = f2b(Pr.a2.z); v1[3] = f2b(Pr.a2.w);
            v1[4] = f2b(Pr.a3.x); v1[5] = f2b(Pr.a3.y); v1[6] = f2b(Pr.a3.z); v1[7] = f2b(Pr.a3.w);
            *(bf16x8*)(As_w)     = v0;
            *(bf16x8*)(As_w + 8) = v1;
        }
        *(bf16x8*)(Bs_w)     = Pr.b0;
        *(bf16x8*)(Bs_w + 8) = Pr.b1;
    };

    auto mfma16 = [&]() {
        bf16x8 A00 = *(const bf16x8*)(Af);
        bf16x8 A10 = *(const bf16x8*)(Af + 16 * 88);
        bf16x8 A01 = *(const bf16x8*)(Af + 32);
        bf16x8 A11 = *(const bf16x8*)(Af + 16 * 88 + 32);
        bf16x8 B00 = *(const bf16x8*)(Bf);
        bf16x8 B10 = *(const bf16x8*)(Bf + 16 * 88);
        bf16x8 B01 = *(const bf16x8*)(Bf + 32);
        bf16x8 B11 = *(const bf16x8*)(Bf + 16 * 88 + 32);
        acc00 = __builtin_amdgcn_mfma_f32_16x16x32_bf16(A00, B00, acc00, 0, 0, 0);
        acc01 = __builtin_amdgcn_mfma_f32_16x16x32_bf16(A00, B10, acc01, 0, 0, 0);
        acc10 = __builtin_amdgcn_mfma_f32_16x16x32_bf16(A10, B00, acc10, 0, 0, 0);
        acc11 = __builtin_amdgcn_mfma_f32_16x16x32_bf16(A10, B10, acc11, 0, 0, 0);
        acc00 = __builtin_amdgcn_mfma_f32_16x16x32_bf16(A01, B01, acc00, 0, 0, 0);
        acc01 = __builtin_amdgcn_mfma_f32_16x16x32_bf16(A01, B11, acc01, 0, 0, 0);
        acc10 = __builtin_amdgcn_mfma_f32_16x16x32_bf16(A11, B01, acc10, 0, 0, 0);
        acc11 = __builtin_amdgcn_mfma_f32_16x16x32_bf16(A11, B11, acc11, 0, 0, 0);
    };

    loadr(P[0], 0);
    #pragma unroll
    for (int t = 0; t < KSTEPS; ++t) {
        if (t + 1 < KSTEPS) loadr(P[(t + 1) & 1], t + 1);
        stage(P[t & 1]);
        __syncthreads();
        mfma16();
        __syncthreads();
    }

    const int crow = m0 + wr * 32 + fq * 4;
    const int col0 = n0 + wc * 32 + fr;
    if (WCT) {
        bf16x4 u;
        u[0]=f2b(acc00[0]); u[1]=f2b(acc00[1]); u[2]=f2b(acc00[2]); u[3]=f2b(acc00[3]);
        *(bf16x4*)(CT + (size_t)col0 * 4096 + crow) = u;
        u[0]=f2b(acc01[0]); u[1]=f2b(acc01[1]); u[2]=f2b(acc01[2]); u[3]=f2b(acc01[3]);
        *(bf16x4*)(CT + (size_t)(col0 + 16) * 4096 + crow) = u;
        u[0]=f2b(acc10[0]); u[1]=f2b(acc10[1]); u[2]=f2b(acc10[2]); u[3]=f2b(acc10[3]);
        *(bf16x4*)(CT + (size_t)col0 * 4096 + crow + 16) = u;
        u[0]=f2b(acc11[0]); u[1]=f2b(acc11[1]); u[2]=f2b(acc11[2]); u[3]=f2b(acc11[3]);
        *(bf16x4*)(CT + (size_t)(col0 + 16) * 4096 + crow + 16) = u;
    }
    if (WC) {
        #pragma unroll
        for (int q = 0; q < 4; ++q) {
            C[(size_t)(crow + q) * N + col0]           = acc00[q];
            C[(size_t)(crow + q) * N + col0 + 16]      = acc01[q];
            C[(size_t)(crow + 16 + q) * N + col0]      = acc10[q];
            C[(size_t)(crow + 16 + q) * N + col0 + 16] = acc11[q];
        }
    }
}

// ---------------------------------------------------------------------------
// adj GEMM (steps 2,4): X = bf16(lrelu(adj @ S + bias)), full-N tile.
// BM=32, BN=256, BK=128, 512 thr. Output bf16 row-major [4096,256].
// ---------------------------------------------------------------------------
struct PrefG {
    float4 a0, a1;
    bf16x8 b0, b1, b2, b3, b4, b5, b6, b7;
};

__global__ __launch_bounds__(512) void gemm_mfma_adj(
    const float* __restrict__ A0p, const float* __restrict__ A1p,
    const short* __restrict__ BT0, const short* __restrict__ BT1,
    const float* __restrict__ bias0, const float* __restrict__ bias1,
    short* __restrict__ C0, short* __restrict__ C1)
{
    const float* A    = blockIdx.y ? A1p : A0p;
    const short* BT   = blockIdx.y ? BT1 : BT0;
    const float* bias = blockIdx.y ? bias1 : bias0;
    short* C          = blockIdx.y ? C1 : C0;

    __shared__ short As[32 * 136];
    __shared__ short Bs[256 * 136];

    const int tid = threadIdx.x;
    const int m0 = blockIdx.x * 32;
    const int w = tid >> 6, l = tid & 63;
    const int wr = w >> 2, wc = w & 3;
    const int fr = l & 15, fq = l >> 4;

    const int ar = tid >> 4, ak = (tid & 15) * 8;
    const int br = tid >> 4, bk = (tid & 15) * 8;

    const float* Ap = A  + (size_t)(m0 + ar) * 4096 + ak;
    const short* Bp = BT + (size_t)br * 4096 + bk;

    short* As_w = As + ar * 136 + ak;
    short* Bs_w = Bs + br * 136 + bk;
    const short* Af = As + (wr * 16 + fr) * 136 + fq * 8;
    const short* Bf = Bs + (wc * 64 + fr) * 136 + fq * 8;

    f32x4v acc0 = {0.f,0.f,0.f,0.f}, acc1 = {0.f,0.f,0.f,0.f};
    f32x4v acc2 = {0.f,0.f,0.f,0.f}, acc3 = {0.f,0.f,0.f,0.f};

    PrefG P0, P1;

    auto loadr = [&](PrefG& P, int t) {
        const int kk = t * 128;
        P.a0 = *(const float4*)(Ap + kk);
        P.a1 = *(const float4*)(Ap + kk + 4);
        P.b0 = *(const bf16x8*)(Bp + kk);
        P.b1 = *(const bf16x8*)(Bp + kk +  32 * 4096);
        P.b2 = *(const bf16x8*)(Bp + kk +  64 * 4096);
        P.b3 = *(const bf16x8*)(Bp + kk +  96 * 4096);
        P.b4 = *(const bf16x8*)(Bp + kk + 128 * 4096);
        P.b5 = *(const bf16x8*)(Bp + kk + 160 * 4096);
        P.b6 = *(const bf16x8*)(Bp + kk + 192 * 4096);
        P.b7 = *(const bf16x8*)(Bp + kk + 224 * 4096);
    };

    auto stage = [&](PrefG& P) {
        bf16x8 av;
        av[0] = f2b(P.a0.x); av[1] = f2b(P.a0.y); av[2] = f2b(P.a0.z); av[3] = f2b(P.a0.w);
        av[4] = f2b(P.a1.x); av[5] = f2b(P.a1.y); av[6] = f2b(P.a1.z); av[7] = f2b(P.a1.w);
        *(bf16x8*)As_w = av;
        *(bf16x8*)(Bs_w + 0 * 32 * 136) = P.b0;
        *(bf16x8*)(Bs_w + 1 * 32 * 136) = P.b1;
        *(bf16x8*)(Bs_w + 2 * 32 * 136) = P.b2;
        *(bf16x8*)(Bs_w + 3 * 32 * 136) = P.b3;
        *(bf16x8*)(Bs_w + 4 * 32 * 136) = P.b4;
        *(bf16x8*)(Bs_w + 5 * 32 * 136) = P.b5;
        *(bf16x8*)(Bs_w + 6 * 32 * 136) = P.b6;
        *(bf16x8*)(Bs_w + 7 * 32 * 136) = P.b7;
    };

    auto mfma16 = [&]() {
        #pragma unroll
        for (int h = 0; h < 4; ++h) {
            bf16x8 Ah  = *(const bf16x8*)(Af + h * 32);
            bf16x8 Bv0 = *(const bf16x8*)(Bf + h * 32);
            bf16x8 Bv1 = *(const bf16x8*)(Bf + 16 * 136 + h * 32);
            bf16x8 Bv2 = *(const bf16x8*)(Bf + 32 * 136 + h * 32);
            bf16x8 Bv3 = *(const bf16x8*)(Bf + 48 * 136 + h * 32);
            acc0 = __builtin_amdgcn_mfma_f32_16x16x32_bf16(Ah, Bv0, acc0, 0, 0, 0);
            acc1 = __builtin_amdgcn_mfma_f32_16x16x32_bf16(Ah, Bv1, acc1, 0, 0, 0);
            acc2 = __builtin_amdgcn_mfma_f32_16x16x32_bf16(Ah, Bv2, acc2, 0, 0, 0);
            acc3 = __builtin_amdgcn_mfma_f32_16x16x32_bf16(Ah, Bv3, acc3, 0, 0, 0);
        }
    };

    loadr(P0, 0);
    loadr(P1, 1);
    for (int it = 0; it < 16; ++it) {
        stage(P0);
        if (it < 15) loadr(P0, 2 * it + 2);
        __syncthreads();
        mfma16();
        __syncthreads();
        stage(P1);
        if (it < 15) loadr(P1, 2 * it + 3);
        __syncthreads();
        mfma16();
        __syncthreads();
    }

    const int crow = m0 + wr * 16 + fq * 4;
    const int ccol = wc * 64 + fr;
    const float bv0 = bias[ccol], bv1 = bias[ccol + 16];
    const float bv2 = bias[ccol + 32], bv3 = bias[ccol + 48];
    #pragma unroll
    for (int q = 0; q < 4; ++q) {
        short* Cr = C + (size_t)(crow + q) * HH;
        Cr[ccol]      = f2b(lrelu(acc0[q] + bv0));
        Cr[ccol + 16] = f2b(lrelu(acc1[q] + bv1));
        Cr[ccol + 32] = f2b(lrelu(acc2[q] + bv2));
        Cr[ccol + 48] = f2b(lrelu(acc3[q] + bv3));
    }
}

// ---------------------------------------------------------------------------
// s1[i] = H[i,:] . a[0:128] ; s2[i] = H[i,:] . a[128:256]
// ---------------------------------------------------------------------------
__global__ void s12_kernel(
    const float* __restrict__ H0, const float* __restrict__ H1,
    const float* __restrict__ a0, const float* __restrict__ a1,
    float* __restrict__ s1_0, float* __restrict__ s1_1,
    float* __restrict__ s2_0, float* __restrict__ s2_1)
{
    const int z = blockIdx.y;
    const float* H = z ? H1 : H0;
    const float* a = z ? a1 : a0;
    float* s1 = z ? s1_1 : s1_0;
    float* s2 = z ? s2_1 : s2_0;

    const int i = blockIdx.x, t = threadIdx.x;   // 64 threads
    float h0 = H[(size_t)i * FF + t];
    float h1 = H[(size_t)i * FF + 64 + t];
    float v1 = h0 * a[t] + h1 * a[64 + t];
    float v2 = h0 * a[128 + t] + h1 * a[192 + t];
    #pragma unroll
    for (int off = 32; off > 0; off >>= 1) {
        v1 += __shfl_down(v1, off);
        v2 += __shfl_down(v2, off);
    }
    if (t == 0) { s1[i] = v1; s2[i] = v2; }
}

// ---------------------------------------------------------------------------
// Split-j MFMA flash-GAT: partial (acc, m, l) per (mod, split).
// 16 q-rows/block, 256 thr, 2 j-splits of 2048, 128-col chunks.
// grid (256, 2, 2): x=rowblock, y=split, z=mod. 4 blocks/CU.
// ---------------------------------------------------------------------------
struct PrefA {
    float4 a0, a1;
    bf16x8 h0, h1, h2, h3, h4, h5, h6, h7;
};

__global__ __launch_bounds__(256, 4) void gat_split(
    const float* __restrict__ adj0, const float* __restrict__ adj1,
    const short* __restrict__ HT0, const short* __restrict__ HT1,
    const float* __restrict__ s1_0, const float* __restrict__ s1_1,
    const float* __restrict__ s2_0, const float* __restrict__ s2_1,
    float* __restrict__ pacc, float* __restrict__ pm, float* __restrict__ pl)
{
    const int z = blockIdx.z, sp = blockIdx.y;
    const float* adjp = z ? adj1 : adj0;
    const short* HTp  = z ? HT1 : HT0;
    const float* s1v  = z ? s1_1 : s1_0;
    const float* s2v  = z ? s2_1 : s2_0;

    __shared__ short Pl[16 * 132];
    __shared__ short HTl[128 * 132];
    __shared__ float scl[16];

    const int tid = threadIdx.x;
    const int i0 = blockIdx.x * 16;
    const int r = tid >> 4, cg = tid & 15, c0 = cg * 8;
    const int l = tid & 63, w = tid >> 6;
    const int fr = l & 15, fq = l >> 4;
    const int sfr = tid >> 4, sf = tid & 15;   // HT staging coords

    const float s1r = s1v[i0 + r];
    float mrun = -3.0e38f, lsum = 0.f;
    f32x4v acc0 = {0.f,0.f,0.f,0.f}, acc1 = {0.f,0.f,0.f,0.f};

    const float* adjrow = adjp + (size_t)(i0 + r) * 4096;
    const int jb = sp * 2048;

    PrefA P[2];

    auto loadr = [&](PrefA& Pr, int J) {
        Pr.a0 = *(const float4*)(adjrow + J + c0);
        Pr.a1 = *(const float4*)(adjrow + J + c0 + 4);
        const short* hb = HTp + (size_t)sfr * 4096 + J + sf * 8;
        Pr.h0 = *(const bf16x8*)(hb);
        Pr.h1 = *(const bf16x8*)(hb + (size_t)16 * 4096);
        Pr.h2 = *(const bf16x8*)(hb + (size_t)32 * 4096);
        Pr.h3 = *(const bf16x8*)(hb + (size_t)48 * 4096);
        Pr.h4 = *(const bf16x8*)(hb + (size_t)64 * 4096);
        Pr.h5 = *(const bf16x8*)(hb + (size_t)80 * 4096);
        Pr.h6 = *(const bf16x8*)(hb + (size_t)96 * 4096);
        Pr.h7 = *(const bf16x8*)(hb + (size_t)112 * 4096);
    };

    auto process = [&](PrefA& Pr, int J) {
        float4 sA = *(const float4*)(s2v + J + c0);
        float4 sB = *(const float4*)(s2v + J + c0 + 4);
        float e0 = (Pr.a0.x > 0.f) ? lrelu(s1r + sA.x) : -1e12f;
        float e1 = (Pr.a0.y > 0.f) ? lrelu(s1r + sA.y) : -1e12f;
        float e2 = (Pr.a0.z > 0.f) ? lrelu(s1r + sA.z) : -1e12f;
        float e3 = (Pr.a0.w > 0.f) ? lrelu(s1r + sA.w) : -1e12f;
        float e4 = (Pr.a1.x > 0.f) ? lrelu(s1r + sB.x) : -1e12f;
        float e5 = (Pr.a1.y > 0.f) ? lrelu(s1r + sB.y) : -1e12f;
        float e6 = (Pr.a1.z > 0.f) ? lrelu(s1r + sB.z) : -1e12f;
        float e7 = (Pr.a1.w > 0.f) ? lrelu(s1r + sB.w) : -1e12f;
        float lm = fmaxf(fmaxf(fmaxf(e0, e1), fmaxf(e2, e3)),
                         fmaxf(fmaxf(e4, e5), fmaxf(e6, e7)));
        lm = fmaxf(lm, __shfl_xor(lm, 1));
        lm = fmaxf(lm, __shfl_xor(lm, 2));
        lm = fmaxf(lm, __shfl_xor(lm, 4));
        lm = fmaxf(lm, __shfl_xor(lm, 8));
        float mnew = fmaxf(mrun, lm);
        float sc = __expf(mrun - mnew);
        float w0 = __expf(e0 - mnew), w1 = __expf(e1 - mnew);
        float w2 = __expf(e2 - mnew), w3 = __expf(e3 - mnew);
        float w4 = __expf(e4 - mnew), w5 = __expf(e5 - mnew);
        float w6 = __expf(e6 - mnew), w7 = __expf(e7 - mnew);
        float wsm = ((w0 + w1) + (w2 + w3)) + ((w4 + w5) + (w6 + w7));
        wsm += __shfl_xor(wsm, 1); wsm += __shfl_xor(wsm, 2);
        wsm += __shfl_xor(wsm, 4); wsm += __shfl_xor(wsm, 8);
        lsum = lsum * sc + wsm; mrun = mnew;
        __syncthreads();   // previous MFMA reads done before overwriting tiles
        bf16x8 wv;
        wv[0] = f2b(w0); wv[1] = f2b(w1); wv[2] = f2b(w2); wv[3] = f2b(w3);
        wv[4] = f2b(w4); wv[5] = f2b(w5); wv[6] = f2b(w6); wv[7] = f2b(w7);
        *(bf16x8*)(Pl + r * 132 + c0) = wv;
        short* hw = HTl + sfr * 132 + sf * 8;
        *(bf16x8*)(hw +   0 * 132) = Pr.h0;
        *(bf16x8*)(hw +  16 * 132) = Pr.h1;
        *(bf16x8*)(hw +  32 * 132) = Pr.h2;
        *(bf16x8*)(hw +  48 * 132) = Pr.h3;
        *(bf16x8*)(hw +  64 * 132) = Pr.h4;
        *(bf16x8*)(hw +  80 * 132) = Pr.h5;
        *(bf16x8*)(hw +  96 * 132) = Pr.h6;
        *(bf16x8*)(hw + 112 * 132) = Pr.h7;
        if (cg == 0) scl[r] = sc;
        __syncthreads();
        #pragma unroll
        for (int q = 0; q < 4; ++q) {
            float s = scl[fq * 4 + q];
            acc0[q] *= s; acc1[q] *= s;
        }
        #pragma unroll
        for (int h = 0; h < 4; ++h) {
            bf16x8 Av  = *(const bf16x8*)(Pl + fr * 132 + fq * 8 + h * 32);
            bf16x8 Bv0 = *(const bf16x8*)(HTl + (w * 32 + fr) * 132 + fq * 8 + h * 32);
            bf16x8 Bv1 = *(const bf16x8*)(HTl + (w * 32 + 16 + fr) * 132 + fq * 8 + h * 32);
            acc0 = __builtin_amdgcn_mfma_f32_16x16x32_bf16(Av, Bv0, acc0, 0, 0, 0);
            acc1 = __builtin_amdgcn_mfma_f32_16x16x32_bf16(Av, Bv1, acc1, 0, 0, 0);
        }
    };

    loadr(P[0], jb);
    #pragma unroll
    for (int it = 0; it < 16; ++it) {
        const int J = jb + it * 128;
        if (it + 1 < 16) loadr(P[(it + 1) & 1], J + 128);
        process(P[it & 1], J);
    }

    const size_t base = (size_t)(z * 2 + sp) * 4096 + i0;
    const int col = w * 32 + fr;
    #pragma unroll
    for (int q = 0; q < 4; ++q) {
        const int rl = fq * 4 + q;
        pacc[(base + rl) * 128 + col]      = acc0[q];
        pacc[(base + rl) * 128 + col + 16] = acc1[q];
    }
    if (cg == 0) { pm[base + r] = mrun; pl[base + r] = lsum; }
}

// ---------------------------------------------------------------------------
// Combine 2 splits -> O = lrelu(merged)  [4096,128] fp32 per mod
// ---------------------------------------------------------------------------
__global__ __launch_bounds__(256) void gat_combine(
    const float* __restrict__ pacc, const float* __restrict__ pm,
    const float* __restrict__ pl,
    float* __restrict__ O0, float* __restrict__ O1)
{
    const int idx = blockIdx.x * 256 + threadIdx.x;   // 0 .. 2*4096*128-1
    const int z = idx >> 19;
    const int rem = idx & 524287;
    const int row = rem >> 7, f = rem & 127;
    const size_t b0 = (size_t)(z * 2 + 0) * 4096 + row;
    const size_t b1 = (size_t)(z * 2 + 1) * 4096 + row;
    float m0 = pm[b0], m1 = pm[b1];
    float l0 = pl[b0], l1 = pl[b1];
    float a0 = pacc[b0 * 128 + f], a1 = pacc[b1 * 128 + f];
    float ms = fmaxf(m0, m1);
    float w0 = __expf(m0 - ms), w1 = __expf(m1 - ms);
    float o = (w0 * a0 + w1 * a1) / (w0 * l0 + w1 * l1);
    float* Op = z ? O1 : O0;
    Op[(size_t)row * FF + f] = lrelu(o);
}

// ---------------------------------------------------------------------------
// PoE + 3 predictors + softmax (unchanged)
// ---------------------------------------------------------------------------
__global__ __launch_bounds__(128) void final_fused(
    const float* __restrict__ O0, const float* __restrict__ O1,
    const float* __restrict__ mask,
    const float* __restrict__ jpW1, const float* __restrict__ jpb1,
    const float* __restrict__ jpW2, const float* __restrict__ jpb2,
    const float* __restrict__ sW1_0, const float* __restrict__ sb1_0,
    const float* __restrict__ sW2_0, const float* __restrict__ sb2_0,
    const float* __restrict__ sW1_1, const float* __restrict__ sb1_1,
    const float* __restrict__ sW2_1, const float* __restrict__ sb2_1,
    float* __restrict__ out)
{
    __shared__ float zbuf[3][64];
    __shared__ float hbuf[3][128];
    __shared__ float lg[16];

    const int i = blockIdx.x, t = threadIdx.x;

    if (t < 64) {
        float mu0 = O0[(size_t)i * FF + t];
        float lv0 = O0[(size_t)i * FF + 64 + t];
        float mu1 = O1[(size_t)i * FF + t];
        float lv1 = O1[(size_t)i * FF + 64 + t];
        float p0 = 1.f / (__expf(lv0) + 1e-8f);
        float p1 = 1.f / (__expf(lv1) + 1e-8f);
        float mk0 = mask[(size_t)i * 2 + 0];
        float mk1 = mask[(size_t)i * 2 + 1];
        float tmp = 1.f + mk0 * p0 + mk1 * p1;
        float jv = 1.f / (tmp + 1e-8f);
        zbuf[0][t] = jv * (mk0 * p0 * mu0 + mk1 * p1 * mu1);
        zbuf[1][t] = mu0;
        zbuf[2][t] = mu1;
    }
    __syncthreads();

    {
        float s0 = jpb1[t], s1 = sb1_0[t], s2 = sb1_1[t];
        for (int k = 0; k < 64; ++k) {
            float z0 = zbuf[0][k], z1 = zbuf[1][k], z2 = zbuf[2][k];
            s0 = fmaf(z0, jpW1[k * PH + t], s0);
            s1 = fmaf(z1, sW1_0[k * PH + t], s1);
            s2 = fmaf(z2, sW1_1[k * PH + t], s2);
        }
        hbuf[0][t] = lrelu(s0);
        hbuf[1][t] = lrelu(s1);
        hbuf[2][t] = lrelu(s2);
    }
    __syncthreads();

    if (t < 15) {
        int p = t / 5, c = t % 5;
        const float* W2 = (p == 0) ? jpW2 : (p == 1 ? sW2_0 : sW2_1);
        const float* b2 = (p == 0) ? jpb2 : (p == 1 ? sb2_0 : sb2_1);
        float s = b2[c];
        for (int k = 0; k < 128; ++k) s = fmaf(hbuf[p][k], W2[k * YY + c], s);
        lg[t] = s;
    }
    __syncthreads();

    if (t < 3) {
        float mx = -3e38f;
        #pragma unroll
        for (int c = 0; c < 5; ++c) mx = fmaxf(mx, lg[t * 5 + c]);
        float ex[5], sum = 0.f;
        #pragma unroll
        for (int c = 0; c < 5; ++c) { ex[c] = __expf(lg[t * 5 + c] - mx); sum += ex[c]; }
        #pragma unroll
        for (int c = 0; c < 5; ++c)
            out[(size_t)i * 15 + t * 5 + c] = ex[c] / sum;
    }
}

// ---------------------------------------------------------------------------
extern "C" void kernel_launch(void* const* d_in, const int* in_sizes, int n_in,
                              void* d_out, int out_size, void* d_ws, size_t ws_size,
                              hipStream_t stream)
{
    const float* x[2]   = {(const float*)d_in[0],  (const float*)d_in[12]};
    const float* adj[2] = {(const float*)d_in[1],  (const float*)d_in[13]};
    const float* g1W[2] = {(const float*)d_in[2],  (const float*)d_in[14]};
    const float* g1b[2] = {(const float*)d_in[3],  (const float*)d_in[15]};
    const float* g2W[2] = {(const float*)d_in[4],  (const float*)d_in[16]};
    const float* g2b[2] = {(const float*)d_in[5],  (const float*)d_in[17]};
    const float* gaW[2] = {(const float*)d_in[6],  (const float*)d_in[18]};
    const float* gaA[2] = {(const float*)d_in[7],  (const float*)d_in[19]};
    const float* sW1[2] = {(const float*)d_in[8],  (const float*)d_in[20]};
    const float* sb1[2] = {(const float*)d_in[9],  (const float*)d_in[21]};
    const float* sW2[2] = {(const float*)d_in[10], (const float*)d_in[22]};
    const float* sb2[2] = {(const float*)d_in[11], (const float*)d_in[23]};
    const float* mask   = (const float*)d_in[24];
    const float* jpW1   = (const float*)d_in[25];
    const float* jpb1   = (const float*)d_in[26];
    const float* jpW2   = (const float*)d_in[27];
    const float* jpb2   = (const float*)d_in[28];
    float* out = (float*)d_out;

    const size_t NH = (size_t)NN * HH;   // 1,048,576
    const size_t NF = (size_t)NN * FF;   //   524,288
    float* p = (float*)d_ws;
    short* STb = (short*)p;  p += NH;             // S^T / S2^T bf16 [256,4096] x2
    short* XBb = (short*)p;  p += NH;             // X1/X2 bf16 [4096,256] x2
    float* Hb  = p;          p += 2 * NF;         // H fp32 [4096,128] x2
    short* HTb = (short*)p;  p += NF;             // H^T bf16 [128,4096] x2
    short* W1T = (short*)p;  p += (2 * 256 * 448) / 2;   // [256,448] x2
    short* W2T = (short*)p;  p += (2 * 256 * 256) / 2;   // [256,256] x2
    short* gWT = (short*)p;  p += (2 * 128 * 256) / 2;   // [128,256] x2
    float* s1b = p;          p += 2 * NN;
    float* s2b = p;          p += 2 * NN;
    float* pacc = p;         p += (size_t)2 * 2 * NN * 128;  // 8.4 MB
    float* pm  = p;          p += 2 * 2 * NN;
    float* plv = p;          p += 2 * 2 * NN;
    float* Ob  = p;          p += 2 * NF;
    // total ~28.3 MB

    short* ST[2] = {STb, STb + NH};
    short* XB[2] = {XBb, XBb + NH};
    float* H[2]  = {Hb, Hb + NF};
    short* HT[2] = {HTb, HTb + NF};
    short* W1Tp[2] = {W1T, W1T + 256 * 448};
    short* W2Tp[2] = {W2T, W2T + 256 * 256};
    short* gWTp[2] = {gWT, gWT + 128 * 256};
    float* s1p[2] = {s1b, s1b + NN};
    float* s2p[2] = {s2b, s2b + NN};
    float* O[2]  = {Ob, Ob + NF};

    // 0. weight preps: W^T bf16 (pad K)
    transpose_f2b_pad<<<dim3(256/32, 448/32, 2), 256, 0, stream>>>(
        g1W[0], g1W[1], W1Tp[0], W1Tp[1], 400, 256, 448);
    transpose_f2b_pad<<<dim3(256/32, 256/32, 2), 256, 0, stream>>>(
        g2W[0], g2W[1], W2Tp[0], W2Tp[1], 256, 256, 256);
    transpose_f2b_pad<<<dim3(128/32, 256/32, 2), 256, 0, stream>>>(
        gaW[0], gaW[1], gWTp[0], gWTp[1], 256, 128, 256);

    // 1. S^T = (x @ W1)^T bf16        (MFMA, A fp32 K=400 pad 448)
    gemm_mfma_gen<false, false, true, 7><<<dim3(HH/64, NN/64, 2), 256, 0, stream>>>(
        (const void*)x[0], (const void*)x[1], W1Tp[0], W1Tp[1],
        nullptr, nullptr, ST[0], ST[1], DD, 448, HH, 400);
    // 2. X1 = bf16(lrelu(adj @ S + b1))
    gemm_mfma_adj<<<dim3(NN/32, 2), 512, 0, stream>>>(
        adj[0], adj[1], ST[0], ST[1], g1b[0], g1b[1], XB[0], XB[1]);
    // 3. S2^T = (X1 @ W2)^T bf16      (MFMA, A bf16 K=256)
    gemm_mfma_gen<true, false, true, 4><<<dim3(HH/64, NN/64, 2), 256, 0, stream>>>(
        (const void*)XB[0], (const void*)XB[1], W2Tp[0], W2Tp[1],
        nullptr, nullptr, ST[0], ST[1], HH, HH, HH, 256);
    // 4. X2 = bf16(lrelu(adj @ S2 + b2))
    gemm_mfma_adj<<<dim3(NN/32, 2), 512, 0, stream>>>(
        adj[0], adj[1], ST[0], ST[1], g2b[0], g2b[1], XB[0], XB[1]);
    // 5. H fp32 + H^T bf16 = X2 @ gaW  (MFMA, A bf16, N=128)
    gemm_mfma_gen<true, true, true, 4><<<dim3(FF/64, NN/64, 2), 256, 0, stream>>>(
        (const void*)XB[0], (const void*)XB[1], gWTp[0], gWTp[1],
        H[0], H[1], HT[0], HT[1], HH, HH, FF, 256);
    // 6. s1/s2
    s12_kernel<<<dim3(NN, 2), 64, 0, stream>>>(
        H[0], H[1], gaA[0], gaA[1], s1p[0], s1p[1], s2p[0], s2p[1]);
    // 7. GAT flash, 2-way j-split -> partials
    gat_split<<<dim3(NN/16, 2, 2), 256, 0, stream>>>(
        adj[0], adj[1], HT[0], HT[1], s1p[0], s1p[1], s2p[0], s2p[1],
        pacc, pm, plv);
    // 7b. combine -> O fp32
    gat_combine<<<dim3((2 * NN * FF) / 256), 256, 0, stream>>>(
        pacc, pm, plv, O[0], O[1]);
    // 8. PoE + predictors + softmax -> out [4096,15]
    final_fused<<<NN, 128, 0, stream>>>(
        O[0], O[1], mask,
        jpW1, jpb1, jpW2, jpb2,
        sW1[0], sb1[0], sW2[0], sb2[0],
        sW1[1], sb1[1], sW2[1], sb2[1],
        out);
}